// Round 1
// baseline (966.936 us; speedup 1.0000x reference)
//
#include <hip/hip_runtime.h>

#define NN 50000
#define NE 800000
#define ND 1000000
#define DI 128
#define DH 128
#define DO 64

__global__ void k_count(const int* __restrict__ dst, int* __restrict__ degi) {
    int i = blockIdx.x * blockDim.x + threadIdx.x;
    if (i < NE) atomicAdd(&degi[dst[i]], 1);
}

__global__ void k_dinv(const int* __restrict__ degi, float* __restrict__ dinv) {
    int i = blockIdx.x * blockDim.x + threadIdx.x;
    if (i < NN) dinv[i] = rsqrtf((float)degi[i] + 1.0f);  // +1 self-loop
}

__global__ void k_scan(const int* __restrict__ degi, int* __restrict__ off) {
    __shared__ int s[1024];
    __shared__ int carry_s;
    int t = threadIdx.x;
    if (t == 0) carry_s = 0;
    __syncthreads();
    for (int base = 0; base < NN; base += 1024) {
        int v = (base + t < NN) ? degi[base + t] : 0;
        s[t] = v;
        __syncthreads();
        for (int d = 1; d < 1024; d <<= 1) {
            int add = (t >= d) ? s[t - d] : 0;
            __syncthreads();
            s[t] += add;
            __syncthreads();
        }
        if (base + t < NN) off[base + t] = carry_s + s[t] - v;  // exclusive
        __syncthreads();
        if (t == 0) carry_s += s[1023];
        __syncthreads();
    }
    if (t == 0) off[NN] = carry_s;
}

__global__ void k_fill(const int* __restrict__ src, const int* __restrict__ dst,
                       const int* __restrict__ off, int* __restrict__ cur,
                       int* __restrict__ csrc) {
    int i = blockIdx.x * blockDim.x + threadIdx.x;
    if (i < NE) {
        int d = dst[i];
        int p = atomicAdd(&cur[d], 1);
        csrc[off[d] + p] = src[i];
    }
}

// out[row][:] = (A[row][:] @ W) * dinv[row]
template <int DOUT_T>
__global__ __launch_bounds__(256) void k_gemm_scale(
    const float* __restrict__ A, const float* __restrict__ W,
    const float* __restrict__ dinv, float* __restrict__ out) {
    constexpr int COLS = DOUT_T / 4;  // 4 threads per row
    __shared__ float sA[64 * 132];    // +4 pad: bank (4*row+k)%32 -> 2-way max (free)
    int tid = threadIdx.x;
    int row0 = blockIdx.x * 64;
    for (int i = 0; i < 8; ++i) {                // 2048 float4 / 256 threads
        int idx = tid + i * 256;
        int r = idx >> 5;                        // 32 float4 per row
        int c = idx & 31;
        float4 v = make_float4(0.f, 0.f, 0.f, 0.f);
        if (row0 + r < NN) v = *(const float4*)&A[(size_t)(row0 + r) * DI + c * 4];
        *(float4*)&sA[r * 132 + c * 4] = v;
    }
    __syncthreads();
    int row = tid >> 2;
    int cq = tid & 3;
    float acc[COLS];
#pragma unroll
    for (int j = 0; j < COLS; ++j) acc[j] = 0.f;
    const float* wbase = W + cq * COLS;
    for (int k = 0; k < DI; ++k) {
        float a = sA[row * 132 + k];
        const float4* w4 = (const float4*)(wbase + (size_t)k * DOUT_T);
#pragma unroll
        for (int j = 0; j < COLS / 4; ++j) {
            float4 w = w4[j];
            acc[4 * j + 0] += a * w.x;
            acc[4 * j + 1] += a * w.y;
            acc[4 * j + 2] += a * w.z;
            acc[4 * j + 3] += a * w.w;
        }
    }
    int grow = row0 + row;
    if (grow < NN) {
        float dv = dinv[grow];
#pragma unroll
        for (int j = 0; j < COLS / 4; ++j) {
            float4 o;
            o.x = acc[4 * j + 0] * dv;
            o.y = acc[4 * j + 1] * dv;
            o.z = acc[4 * j + 2] * dv;
            o.w = acc[4 * j + 3] * dv;
            *(float4*)&out[(size_t)grow * DOUT_T + cq * COLS + 4 * j] = o;
        }
    }
}

// z[n] = relu(dinv[n] * (sum_{e: dst=n} hs[src_e] + hs[n]) + b)
template <int D>
__global__ __launch_bounds__(256) void k_agg(
    const float* __restrict__ hs, const float* __restrict__ dinv,
    const int* __restrict__ off, const int* __restrict__ csrc,
    const float* __restrict__ bias, float* __restrict__ z) {
    int node = blockIdx.x * 4 + (threadIdx.x >> 6);  // one wave per node
    if (node >= NN) return;
    int lane = threadIdx.x & 63;
    float a0 = 0.f, a1 = 0.f;
    int s = off[node], e = off[node + 1];
    for (int j = s; j < e; ++j) {
        int sr = csrc[j];
        const float* hp = hs + (size_t)sr * D;
        a0 += hp[lane];
        if (D == 128) a1 += hp[64 + lane];
    }
    const float* hn = hs + (size_t)node * D;  // self loop
    a0 += hn[lane];
    if (D == 128) a1 += hn[64 + lane];
    float dv = dinv[node];
    float r0 = dv * a0 + bias[lane];
    z[(size_t)node * D + lane] = r0 > 0.f ? r0 : 0.f;
    if (D == 128) {
        float r1 = dv * a1 + bias[64 + lane];
        z[(size_t)node * D + 64 + lane] = r1 > 0.f ? r1 : 0.f;
    }
}

__global__ __launch_bounds__(256) void k_dec(const float* __restrict__ z2,
                                             const int* __restrict__ eli,
                                             float* __restrict__ out) {
    int pair = blockIdx.x * 16 + (threadIdx.x >> 4);  // 16 lanes per pair
    if (pair >= ND) return;
    int sub = threadIdx.x & 15;
    int ia = eli[pair];
    int ib = eli[ND + pair];
    float4 va = *(const float4*)&z2[(size_t)ia * DO + sub * 4];
    float4 vb = *(const float4*)&z2[(size_t)ib * DO + sub * 4];
    float v = va.x * vb.x + va.y * vb.y + va.z * vb.z + va.w * vb.w;
#pragma unroll
    for (int o = 1; o < 16; o <<= 1) v += __shfl_xor(v, o);
    if (sub == 0) out[pair] = v;
}

extern "C" void kernel_launch(void* const* d_in, const int* in_sizes, int n_in,
                              void* d_out, int out_size, void* d_ws, size_t ws_size,
                              hipStream_t stream) {
    const float* x  = (const float*)d_in[0];
    const float* Wi = (const float*)d_in[1];
    const float* bi = (const float*)d_in[2];
    const float* Wo = (const float*)d_in[3];
    const float* bo = (const float*)d_in[4];
    const int* ei   = (const int*)d_in[5];
    const int* eli  = (const int*)d_in[6];
    float* out = (float*)d_out;

    char* ws = (char*)d_ws;
    size_t o = 0;
    auto alloc = [&](size_t bytes) -> char* {
        char* p = ws + o;
        o = (o + bytes + 255) & ~(size_t)255;
        return p;
    };
    float* dinv = (float*)alloc(NN * 4);
    int* degi   = (int*)alloc(NN * 4);
    int* off    = (int*)alloc((NN + 1) * 4);
    int* cur    = (int*)alloc(NN * 4);
    int* csrc   = (int*)alloc((size_t)NE * 4);
    float* h1   = (float*)alloc((size_t)NN * DH * 4);
    float* z1   = (float*)alloc((size_t)NN * DH * 4);
    float* h2   = (float*)alloc((size_t)NN * DO * 4);
    float* z2   = (float*)alloc((size_t)NN * DO * 4);

    const int* esrc = ei;
    const int* edst = ei + NE;

    hipMemsetAsync(degi, 0, NN * 4, stream);
    hipMemsetAsync(cur, 0, NN * 4, stream);
    k_count<<<(NE + 255) / 256, 256, 0, stream>>>(edst, degi);
    k_dinv<<<(NN + 255) / 256, 256, 0, stream>>>(degi, dinv);
    k_scan<<<1, 1024, 0, stream>>>(degi, off);
    k_fill<<<(NE + 255) / 256, 256, 0, stream>>>(esrc, edst, off, cur, csrc);

    k_gemm_scale<DH><<<(NN + 63) / 64, 256, 0, stream>>>(x, Wi, dinv, h1);
    k_agg<DH><<<(NN + 3) / 4, 256, 0, stream>>>(h1, dinv, off, csrc, bi, z1);
    k_gemm_scale<DO><<<(NN + 63) / 64, 256, 0, stream>>>(z1, Wo, dinv, h2);
    k_agg<DO><<<(NN + 3) / 4, 256, 0, stream>>>(h2, dinv, off, csrc, bo, z2);

    k_dec<<<(ND + 15) / 16, 256, 0, stream>>>(z2, eli, out);
}

// Round 2
// 446.794 us; speedup vs baseline: 2.1642x; 2.1642x over previous
//
#include <hip/hip_runtime.h>

#define NN 50000
#define NE 800000
#define ND 1000000
#define DI 128
#define DH 128
#define DO 64

__global__ void k_count(const int* __restrict__ dst, int* __restrict__ degi) {
    int i = blockIdx.x * blockDim.x + threadIdx.x;
    if (i < NE) atomicAdd(&degi[dst[i]], 1);
}

__global__ void k_dinv(const int* __restrict__ degi, float* __restrict__ dinv) {
    int i = blockIdx.x * blockDim.x + threadIdx.x;
    if (i < NN) dinv[i] = rsqrtf((float)degi[i] + 1.0f);  // +1 self-loop
}

__global__ void k_scan(const int* __restrict__ degi, int* __restrict__ off) {
    __shared__ int s[1024];
    __shared__ int carry_s;
    int t = threadIdx.x;
    if (t == 0) carry_s = 0;
    __syncthreads();
    for (int base = 0; base < NN; base += 1024) {
        int v = (base + t < NN) ? degi[base + t] : 0;
        s[t] = v;
        __syncthreads();
        for (int d = 1; d < 1024; d <<= 1) {
            int add = (t >= d) ? s[t - d] : 0;
            __syncthreads();
            s[t] += add;
            __syncthreads();
        }
        if (base + t < NN) off[base + t] = carry_s + s[t] - v;  // exclusive
        __syncthreads();
        if (t == 0) carry_s += s[1023];
        __syncthreads();
    }
    if (t == 0) off[NN] = carry_s;
}

__global__ void k_fill(const int* __restrict__ src, const int* __restrict__ dst,
                       const int* __restrict__ off, int* __restrict__ cur,
                       int* __restrict__ csrc) {
    int i = blockIdx.x * blockDim.x + threadIdx.x;
    if (i < NE) {
        int d = dst[i];
        int p = atomicAdd(&cur[d], 1);
        csrc[off[d] + p] = src[i];
    }
}

// out[row][:] = (A[row][:] @ W) * dinv[row]
// BM=128, BK=32, 256 threads. A-tile transposed in LDS (stride 132, conflict-free
// b128 reads); W-tile row-major in LDS. Thread tile TM x 8 (cols split 4+4 halves).
template <int BN>
__global__ __launch_bounds__(256) void k_gemm_scale(
    const float* __restrict__ A, const float* __restrict__ W,
    const float* __restrict__ dinv, float* __restrict__ out) {
    constexpr int BM = 128, BK = 32, K = 128;
    constexpr int TM = (BN == 128) ? 8 : 4;
    constexpr int NTX = BN / 8;          // 16 (BN=128) or 8 (BN=64)
    constexpr int SA = 132;              // sAT row stride (floats)
    __shared__ float sAT[BK * SA];       // sAT[k][m] = A[row0+m][k0+k]
    __shared__ float sW[BK * BN];        // sW[k][n]  = W[k0+k][n]

    const int tid = threadIdx.x;
    const int row0 = blockIdx.x * BM;
    const int tx = tid & (NTX - 1);
    const int ty = tid / NTX;            // row group

    float acc[TM][8];
#pragma unroll
    for (int i = 0; i < TM; ++i)
#pragma unroll
        for (int j = 0; j < 8; ++j) acc[i][j] = 0.f;

    for (int t = 0; t < K / BK; ++t) {
        const int k0 = t * BK;
        // ---- stage A (transposed) ----
        float4 av[4];
#pragma unroll
        for (int i = 0; i < 4; ++i) {
            int f = tid + i * 256;       // float4 index in [0,1024)
            int m = f >> 3, c = f & 7;
            int gr = row0 + m;
            av[i] = (gr < NN) ? *(const float4*)&A[(size_t)gr * K + k0 + 4 * c]
                              : make_float4(0.f, 0.f, 0.f, 0.f);
        }
        // ---- stage W ----
        constexpr int WF4 = BK * BN / 4; // 1024 or 512
        float4 wv[WF4 / 256];
        const float* wsrc = W + (size_t)k0 * BN;
#pragma unroll
        for (int i = 0; i < WF4 / 256; ++i)
            wv[i] = *(const float4*)&wsrc[(tid + i * 256) * 4];
#pragma unroll
        for (int i = 0; i < 4; ++i) {
            int f = tid + i * 256;
            int m = f >> 3, c = f & 7;
            sAT[(4 * c + 0) * SA + m] = av[i].x;
            sAT[(4 * c + 1) * SA + m] = av[i].y;
            sAT[(4 * c + 2) * SA + m] = av[i].z;
            sAT[(4 * c + 3) * SA + m] = av[i].w;
        }
#pragma unroll
        for (int i = 0; i < WF4 / 256; ++i)
            *(float4*)&sW[(tid + i * 256) * 4] = wv[i];
        __syncthreads();

        // ---- compute ----
#pragma unroll 4
        for (int k = 0; k < BK; ++k) {
            float a[TM];
            float4 a0 = *(const float4*)&sAT[k * SA + ty * TM];
            a[0] = a0.x; a[1] = a0.y; a[2] = a0.z; a[3] = a0.w;
            if (TM == 8) {
                float4 a1 = *(const float4*)&sAT[k * SA + ty * TM + 4];
                a[4] = a1.x; a[5] = a1.y; a[6] = a1.z; a[7] = a1.w;
            }
            float4 b0 = *(const float4*)&sW[k * BN + tx * 4];
            float4 b1 = *(const float4*)&sW[k * BN + BN / 2 + tx * 4];
#pragma unroll
            for (int i = 0; i < TM; ++i) {
                acc[i][0] += a[i] * b0.x;
                acc[i][1] += a[i] * b0.y;
                acc[i][2] += a[i] * b0.z;
                acc[i][3] += a[i] * b0.w;
                acc[i][4] += a[i] * b1.x;
                acc[i][5] += a[i] * b1.y;
                acc[i][6] += a[i] * b1.z;
                acc[i][7] += a[i] * b1.w;
            }
        }
        __syncthreads();
    }

    // ---- epilogue: scale by dinv[row], store ----
#pragma unroll
    for (int i = 0; i < TM; ++i) {
        int row = row0 + ty * TM + i;
        if (row < NN) {
            float dv = dinv[row];
            float4 o0, o1;
            o0.x = acc[i][0] * dv; o0.y = acc[i][1] * dv;
            o0.z = acc[i][2] * dv; o0.w = acc[i][3] * dv;
            o1.x = acc[i][4] * dv; o1.y = acc[i][5] * dv;
            o1.z = acc[i][6] * dv; o1.w = acc[i][7] * dv;
            *(float4*)&out[(size_t)row * BN + tx * 4] = o0;
            *(float4*)&out[(size_t)row * BN + BN / 2 + tx * 4] = o1;
        }
    }
}

// z[n] = relu(dinv[n] * (sum_{e: dst=n} hs[src_e] + hs[n]) + b)
template <int D>
__global__ __launch_bounds__(256) void k_agg(
    const float* __restrict__ hs, const float* __restrict__ dinv,
    const int* __restrict__ off, const int* __restrict__ csrc,
    const float* __restrict__ bias, float* __restrict__ z) {
    int node = blockIdx.x * 4 + (threadIdx.x >> 6);  // one wave per node
    if (node >= NN) return;
    int lane = threadIdx.x & 63;
    float a0 = 0.f, a1 = 0.f;
    int s = off[node], e = off[node + 1];
    for (int j = s; j < e; ++j) {
        int sr = csrc[j];
        const float* hp = hs + (size_t)sr * D;
        a0 += hp[lane];
        if (D == 128) a1 += hp[64 + lane];
    }
    const float* hn = hs + (size_t)node * D;  // self loop
    a0 += hn[lane];
    if (D == 128) a1 += hn[64 + lane];
    float dv = dinv[node];
    float r0 = dv * a0 + bias[lane];
    z[(size_t)node * D + lane] = r0 > 0.f ? r0 : 0.f;
    if (D == 128) {
        float r1 = dv * a1 + bias[64 + lane];
        z[(size_t)node * D + 64 + lane] = r1 > 0.f ? r1 : 0.f;
    }
}

__global__ __launch_bounds__(256) void k_dec(const float* __restrict__ z2,
                                             const int* __restrict__ eli,
                                             float* __restrict__ out) {
    int pair = blockIdx.x * 16 + (threadIdx.x >> 4);  // 16 lanes per pair
    if (pair >= ND) return;
    int sub = threadIdx.x & 15;
    int ia = eli[pair];
    int ib = eli[ND + pair];
    float4 va = *(const float4*)&z2[(size_t)ia * DO + sub * 4];
    float4 vb = *(const float4*)&z2[(size_t)ib * DO + sub * 4];
    float v = va.x * vb.x + va.y * vb.y + va.z * vb.z + va.w * vb.w;
#pragma unroll
    for (int o = 1; o < 16; o <<= 1) v += __shfl_xor(v, o);
    if (sub == 0) out[pair] = v;
}

extern "C" void kernel_launch(void* const* d_in, const int* in_sizes, int n_in,
                              void* d_out, int out_size, void* d_ws, size_t ws_size,
                              hipStream_t stream) {
    const float* x  = (const float*)d_in[0];
    const float* Wi = (const float*)d_in[1];
    const float* bi = (const float*)d_in[2];
    const float* Wo = (const float*)d_in[3];
    const float* bo = (const float*)d_in[4];
    const int* ei   = (const int*)d_in[5];
    const int* eli  = (const int*)d_in[6];
    float* out = (float*)d_out;

    char* ws = (char*)d_ws;
    size_t o = 0;
    auto alloc = [&](size_t bytes) -> char* {
        char* p = ws + o;
        o = (o + bytes + 255) & ~(size_t)255;
        return p;
    };
    float* dinv = (float*)alloc(NN * 4);
    int* degi   = (int*)alloc(NN * 4);
    int* off    = (int*)alloc((NN + 1) * 4);
    int* cur    = (int*)alloc(NN * 4);
    int* csrc   = (int*)alloc((size_t)NE * 4);
    float* h1   = (float*)alloc((size_t)NN * DH * 4);
    float* z1   = (float*)alloc((size_t)NN * DH * 4);
    float* h2   = (float*)alloc((size_t)NN * DO * 4);
    float* z2   = (float*)alloc((size_t)NN * DO * 4);

    const int* esrc = ei;
    const int* edst = ei + NE;

    hipMemsetAsync(degi, 0, NN * 4, stream);
    hipMemsetAsync(cur, 0, NN * 4, stream);
    k_count<<<(NE + 255) / 256, 256, 0, stream>>>(edst, degi);
    k_dinv<<<(NN + 255) / 256, 256, 0, stream>>>(degi, dinv);
    k_scan<<<1, 1024, 0, stream>>>(degi, off);
    k_fill<<<(NE + 255) / 256, 256, 0, stream>>>(esrc, edst, off, cur, csrc);

    k_gemm_scale<DH><<<(NN + 127) / 128, 256, 0, stream>>>(x, Wi, dinv, h1);
    k_agg<DH><<<(NN + 3) / 4, 256, 0, stream>>>(h1, dinv, off, csrc, bi, z1);
    k_gemm_scale<DO><<<(NN + 127) / 128, 256, 0, stream>>>(z1, Wo, dinv, h2);
    k_agg<DO><<<(NN + 3) / 4, 256, 0, stream>>>(h2, dinv, off, csrc, bo, z2);

    k_dec<<<(ND + 15) / 16, 256, 0, stream>>>(z2, eli, out);
}

// Round 3
// 362.335 us; speedup vs baseline: 2.6686x; 1.2331x over previous
//
#include <hip/hip_runtime.h>

#define NN 50000
#define NE 800000
#define ND 1000000
#define DI 128
#define DH 128
#define DO 64

#define SCAN_GRID ((NN + 255) / 256)   // 196

__global__ void k_count(const int* __restrict__ dst, int* __restrict__ degi) {
    int i = blockIdx.x * blockDim.x + threadIdx.x;
    if (i < NE) atomicAdd(&degi[dst[i]], 1);
}

// phase 1: per-block sums of degi
__global__ __launch_bounds__(256) void k_blocksum(const int* __restrict__ degi,
                                                  int* __restrict__ part) {
    int i = blockIdx.x * 256 + threadIdx.x;
    int v = (i < NN) ? degi[i] : 0;
#pragma unroll
    for (int o = 1; o < 64; o <<= 1) v += __shfl_xor(v, o);
    __shared__ int s[4];
    if ((threadIdx.x & 63) == 0) s[threadIdx.x >> 6] = v;
    __syncthreads();
    if (threadIdx.x == 0) part[blockIdx.x] = s[0] + s[1] + s[2] + s[3];
}

// phase 2: exclusive scan of the <=256 partials (single block)
__global__ __launch_bounds__(256) void k_scanpart(int* __restrict__ part, int n) {
    int t = threadIdx.x;
    int v = (t < n) ? part[t] : 0;
    __shared__ int s[256];
    s[t] = v;
    __syncthreads();
#pragma unroll
    for (int d = 1; d < 256; d <<= 1) {
        int add = (t >= d) ? s[t - d] : 0;
        __syncthreads();
        s[t] += add;
        __syncthreads();
    }
    if (t < n) part[t] = s[t] - v;  // exclusive
}

// phase 3: block-local exclusive scan + partial offset; fuse dinv compute
__global__ __launch_bounds__(256) void k_scanfinal(const int* __restrict__ degi,
                                                   const int* __restrict__ part,
                                                   int* __restrict__ off,
                                                   float* __restrict__ dinv) {
    int b = blockIdx.x, t = threadIdx.x;
    int i = b * 256 + t;
    int v = (i < NN) ? degi[i] : 0;
    __shared__ int s[256];
    s[t] = v;
    __syncthreads();
#pragma unroll
    for (int d = 1; d < 256; d <<= 1) {
        int add = (t >= d) ? s[t - d] : 0;
        __syncthreads();
        s[t] += add;
        __syncthreads();
    }
    if (i < NN) {
        off[i] = part[b] + s[t] - v;
        dinv[i] = rsqrtf((float)v + 1.0f);  // +1 self-loop
    }
    if (i == 0) off[NN] = NE;  // total degree == edge count
}

__global__ void k_fill(const int* __restrict__ src, const int* __restrict__ dst,
                       const int* __restrict__ off, int* __restrict__ cur,
                       int* __restrict__ csrc) {
    int i = blockIdx.x * blockDim.x + threadIdx.x;
    if (i < NE) {
        int d = dst[i];
        int p = atomicAdd(&cur[d], 1);
        csrc[off[d] + p] = src[i];
    }
}

// out[row][:] = (A[row][:] @ W) * dinv[row]
// BM=128, BK=32, 256 threads. A-tile transposed in LDS (stride 132, conflict-free
// b128 reads); W-tile row-major in LDS. Thread tile TM x 8 (cols split 4+4 halves).
template <int BN>
__global__ __launch_bounds__(256) void k_gemm_scale(
    const float* __restrict__ A, const float* __restrict__ W,
    const float* __restrict__ dinv, float* __restrict__ out) {
    constexpr int BM = 128, BK = 32, K = 128;
    constexpr int TM = (BN == 128) ? 8 : 4;
    constexpr int NTX = BN / 8;          // 16 (BN=128) or 8 (BN=64)
    constexpr int SA = 132;              // sAT row stride (floats)
    __shared__ float sAT[BK * SA];       // sAT[k][m] = A[row0+m][k0+k]
    __shared__ float sW[BK * BN];        // sW[k][n]  = W[k0+k][n]

    const int tid = threadIdx.x;
    const int row0 = blockIdx.x * BM;
    const int tx = tid & (NTX - 1);
    const int ty = tid / NTX;            // row group

    float acc[TM][8];
#pragma unroll
    for (int i = 0; i < TM; ++i)
#pragma unroll
        for (int j = 0; j < 8; ++j) acc[i][j] = 0.f;

    for (int t = 0; t < K / BK; ++t) {
        const int k0 = t * BK;
        // ---- stage A (transposed) ----
        float4 av[4];
#pragma unroll
        for (int i = 0; i < 4; ++i) {
            int f = tid + i * 256;       // float4 index in [0,1024)
            int m = f >> 3, c = f & 7;
            int gr = row0 + m;
            av[i] = (gr < NN) ? *(const float4*)&A[(size_t)gr * K + k0 + 4 * c]
                              : make_float4(0.f, 0.f, 0.f, 0.f);
        }
        // ---- stage W ----
        constexpr int WF4 = BK * BN / 4; // 1024 or 512
        float4 wv[WF4 / 256];
        const float* wsrc = W + (size_t)k0 * BN;
#pragma unroll
        for (int i = 0; i < WF4 / 256; ++i)
            wv[i] = *(const float4*)&wsrc[(tid + i * 256) * 4];
#pragma unroll
        for (int i = 0; i < 4; ++i) {
            int f = tid + i * 256;
            int m = f >> 3, c = f & 7;
            sAT[(4 * c + 0) * SA + m] = av[i].x;
            sAT[(4 * c + 1) * SA + m] = av[i].y;
            sAT[(4 * c + 2) * SA + m] = av[i].z;
            sAT[(4 * c + 3) * SA + m] = av[i].w;
        }
#pragma unroll
        for (int i = 0; i < WF4 / 256; ++i)
            *(float4*)&sW[(tid + i * 256) * 4] = wv[i];
        __syncthreads();

        // ---- compute ----
#pragma unroll 4
        for (int k = 0; k < BK; ++k) {
            float a[TM];
            float4 a0 = *(const float4*)&sAT[k * SA + ty * TM];
            a[0] = a0.x; a[1] = a0.y; a[2] = a0.z; a[3] = a0.w;
            if (TM == 8) {
                float4 a1 = *(const float4*)&sAT[k * SA + ty * TM + 4];
                a[4] = a1.x; a[5] = a1.y; a[6] = a1.z; a[7] = a1.w;
            }
            float4 b0 = *(const float4*)&sW[k * BN + tx * 4];
            float4 b1 = *(const float4*)&sW[k * BN + BN / 2 + tx * 4];
#pragma unroll
            for (int i = 0; i < TM; ++i) {
                acc[i][0] += a[i] * b0.x;
                acc[i][1] += a[i] * b0.y;
                acc[i][2] += a[i] * b0.z;
                acc[i][3] += a[i] * b0.w;
                acc[i][4] += a[i] * b1.x;
                acc[i][5] += a[i] * b1.y;
                acc[i][6] += a[i] * b1.z;
                acc[i][7] += a[i] * b1.w;
            }
        }
        __syncthreads();
    }

    // ---- epilogue: scale by dinv[row], store ----
#pragma unroll
    for (int i = 0; i < TM; ++i) {
        int row = row0 + ty * TM + i;
        if (row < NN) {
            float dv = dinv[row];
            float4 o0, o1;
            o0.x = acc[i][0] * dv; o0.y = acc[i][1] * dv;
            o0.z = acc[i][2] * dv; o0.w = acc[i][3] * dv;
            o1.x = acc[i][4] * dv; o1.y = acc[i][5] * dv;
            o1.z = acc[i][6] * dv; o1.w = acc[i][7] * dv;
            *(float4*)&out[(size_t)row * BN + tx * 4] = o0;
            *(float4*)&out[(size_t)row * BN + BN / 2 + tx * 4] = o1;
        }
    }
}

// z[n] = relu(dinv[n] * (sum_{e: dst=n} hs[src_e] + hs[n]) + b)
template <int D>
__global__ __launch_bounds__(256) void k_agg(
    const float* __restrict__ hs, const float* __restrict__ dinv,
    const int* __restrict__ off, const int* __restrict__ csrc,
    const float* __restrict__ bias, float* __restrict__ z) {
    int node = blockIdx.x * 4 + (threadIdx.x >> 6);  // one wave per node
    if (node >= NN) return;
    int lane = threadIdx.x & 63;
    float a0 = 0.f, a1 = 0.f;
    int s = off[node], e = off[node + 1];
    for (int j = s; j < e; ++j) {
        int sr = csrc[j];
        const float* hp = hs + (size_t)sr * D;
        a0 += hp[lane];
        if (D == 128) a1 += hp[64 + lane];
    }
    const float* hn = hs + (size_t)node * D;  // self loop
    a0 += hn[lane];
    if (D == 128) a1 += hn[64 + lane];
    float dv = dinv[node];
    float r0 = dv * a0 + bias[lane];
    z[(size_t)node * D + lane] = r0 > 0.f ? r0 : 0.f;
    if (D == 128) {
        float r1 = dv * a1 + bias[64 + lane];
        z[(size_t)node * D + 64 + lane] = r1 > 0.f ? r1 : 0.f;
    }
}

__global__ __launch_bounds__(256) void k_dec(const float* __restrict__ z2,
                                             const int* __restrict__ eli,
                                             float* __restrict__ out) {
    int pair = blockIdx.x * 16 + (threadIdx.x >> 4);  // 16 lanes per pair
    if (pair >= ND) return;
    int sub = threadIdx.x & 15;
    int ia = eli[pair];
    int ib = eli[ND + pair];
    float4 va = *(const float4*)&z2[(size_t)ia * DO + sub * 4];
    float4 vb = *(const float4*)&z2[(size_t)ib * DO + sub * 4];
    float v = va.x * vb.x + va.y * vb.y + va.z * vb.z + va.w * vb.w;
#pragma unroll
    for (int o = 1; o < 16; o <<= 1) v += __shfl_xor(v, o);
    if (sub == 0) out[pair] = v;
}

extern "C" void kernel_launch(void* const* d_in, const int* in_sizes, int n_in,
                              void* d_out, int out_size, void* d_ws, size_t ws_size,
                              hipStream_t stream) {
    const float* x  = (const float*)d_in[0];
    const float* Wi = (const float*)d_in[1];
    const float* bi = (const float*)d_in[2];
    const float* Wo = (const float*)d_in[3];
    const float* bo = (const float*)d_in[4];
    const int* ei   = (const int*)d_in[5];
    const int* eli  = (const int*)d_in[6];
    float* out = (float*)d_out;

    char* ws = (char*)d_ws;
    size_t o = 0;
    auto alloc = [&](size_t bytes) -> char* {
        char* p = ws + o;
        o = (o + bytes + 255) & ~(size_t)255;
        return p;
    };
    float* dinv = (float*)alloc(NN * 4);
    int* degi   = (int*)alloc(NN * 4);
    int* off    = (int*)alloc((NN + 1) * 4);
    int* cur    = (int*)alloc(NN * 4);
    int* part   = (int*)alloc(SCAN_GRID * 4);
    int* csrc   = (int*)alloc((size_t)NE * 4);
    float* h1   = (float*)alloc((size_t)NN * DH * 4);
    float* z1   = (float*)alloc((size_t)NN * DH * 4);
    float* h2   = (float*)alloc((size_t)NN * DO * 4);
    float* z2   = (float*)alloc((size_t)NN * DO * 4);

    const int* esrc = ei;
    const int* edst = ei + NE;

    hipMemsetAsync(degi, 0, NN * 4, stream);
    hipMemsetAsync(cur, 0, NN * 4, stream);
    k_count<<<(NE + 255) / 256, 256, 0, stream>>>(edst, degi);
    k_blocksum<<<SCAN_GRID, 256, 0, stream>>>(degi, part);
    k_scanpart<<<1, 256, 0, stream>>>(part, SCAN_GRID);
    k_scanfinal<<<SCAN_GRID, 256, 0, stream>>>(degi, part, off, dinv);
    k_fill<<<(NE + 255) / 256, 256, 0, stream>>>(esrc, edst, off, cur, csrc);

    k_gemm_scale<DH><<<(NN + 127) / 128, 256, 0, stream>>>(x, Wi, dinv, h1);
    k_agg<DH><<<(NN + 3) / 4, 256, 0, stream>>>(h1, dinv, off, csrc, bi, z1);
    k_gemm_scale<DO><<<(NN + 127) / 128, 256, 0, stream>>>(z1, Wo, dinv, h2);
    k_agg<DO><<<(NN + 3) / 4, 256, 0, stream>>>(h2, dinv, off, csrc, bo, z2);

    k_dec<<<(ND + 15) / 16, 256, 0, stream>>>(z2, eli, out);
}

// Round 4
// 291.114 us; speedup vs baseline: 3.3215x; 1.2446x over previous
//
#include <hip/hip_runtime.h>

#define NN 50000
#define NE 800000
#define ND 1000000
#define DI 128
#define DH 128
#define DO 64

#define SCAN_GRID ((NN + 255) / 256)   // 196

__global__ void k_count(const int* __restrict__ dst, int* __restrict__ degi) {
    int i = blockIdx.x * blockDim.x + threadIdx.x;
    if (i < NE) atomicAdd(&degi[dst[i]], 1);
}

// phase 1: per-block sums of degi
__global__ __launch_bounds__(256) void k_blocksum(const int* __restrict__ degi,
                                                  int* __restrict__ part) {
    int i = blockIdx.x * 256 + threadIdx.x;
    int v = (i < NN) ? degi[i] : 0;
#pragma unroll
    for (int o = 1; o < 64; o <<= 1) v += __shfl_xor(v, o);
    __shared__ int s[4];
    if ((threadIdx.x & 63) == 0) s[threadIdx.x >> 6] = v;
    __syncthreads();
    if (threadIdx.x == 0) part[blockIdx.x] = s[0] + s[1] + s[2] + s[3];
}

// phase 2: exclusive scan of the <=256 partials (single block)
__global__ __launch_bounds__(256) void k_scanpart(int* __restrict__ part, int n) {
    int t = threadIdx.x;
    int v = (t < n) ? part[t] : 0;
    __shared__ int s[256];
    s[t] = v;
    __syncthreads();
#pragma unroll
    for (int d = 1; d < 256; d <<= 1) {
        int add = (t >= d) ? s[t - d] : 0;
        __syncthreads();
        s[t] += add;
        __syncthreads();
    }
    if (t < n) part[t] = s[t] - v;  // exclusive
}

// phase 3: block-local exclusive scan + partial offset; fuse dinv compute
__global__ __launch_bounds__(256) void k_scanfinal(const int* __restrict__ degi,
                                                   const int* __restrict__ part,
                                                   int* __restrict__ off,
                                                   float* __restrict__ dinv) {
    int b = blockIdx.x, t = threadIdx.x;
    int i = b * 256 + t;
    int v = (i < NN) ? degi[i] : 0;
    __shared__ int s[256];
    s[t] = v;
    __syncthreads();
#pragma unroll
    for (int d = 1; d < 256; d <<= 1) {
        int add = (t >= d) ? s[t - d] : 0;
        __syncthreads();
        s[t] += add;
        __syncthreads();
    }
    if (i < NN) {
        off[i] = part[b] + s[t] - v;
        dinv[i] = rsqrtf((float)v + 1.0f);  // +1 self-loop
    }
    if (i == 0) off[NN] = NE;  // total degree == edge count
}

__global__ void k_fill(const int* __restrict__ src, const int* __restrict__ dst,
                       const int* __restrict__ off, int* __restrict__ cur,
                       int* __restrict__ csrc) {
    int i = blockIdx.x * blockDim.x + threadIdx.x;
    if (i < NE) {
        int d = dst[i];
        int p = atomicAdd(&cur[d], 1);
        csrc[off[d] + p] = src[i];
    }
}

// out[row][:] = (A[row][:] @ W) * dinv[row]
template <int BN>
__global__ __launch_bounds__(256) void k_gemm_scale(
    const float* __restrict__ A, const float* __restrict__ W,
    const float* __restrict__ dinv, float* __restrict__ out) {
    constexpr int BM = 128, BK = 32, K = 128;
    constexpr int TM = (BN == 128) ? 8 : 4;
    constexpr int NTX = BN / 8;          // 16 (BN=128) or 8 (BN=64)
    constexpr int SA = 132;              // sAT row stride (floats)
    __shared__ float sAT[BK * SA];       // sAT[k][m] = A[row0+m][k0+k]
    __shared__ float sW[BK * BN];        // sW[k][n]  = W[k0+k][n]

    const int tid = threadIdx.x;
    const int row0 = blockIdx.x * BM;
    const int tx = tid & (NTX - 1);
    const int ty = tid / NTX;            // row group

    float acc[TM][8];
#pragma unroll
    for (int i = 0; i < TM; ++i)
#pragma unroll
        for (int j = 0; j < 8; ++j) acc[i][j] = 0.f;

    for (int t = 0; t < K / BK; ++t) {
        const int k0 = t * BK;
        float4 av[4];
#pragma unroll
        for (int i = 0; i < 4; ++i) {
            int f = tid + i * 256;       // float4 index in [0,1024)
            int m = f >> 3, c = f & 7;
            int gr = row0 + m;
            av[i] = (gr < NN) ? *(const float4*)&A[(size_t)gr * K + k0 + 4 * c]
                              : make_float4(0.f, 0.f, 0.f, 0.f);
        }
        constexpr int WF4 = BK * BN / 4; // 1024 or 512
        float4 wv[WF4 / 256];
        const float* wsrc = W + (size_t)k0 * BN;
#pragma unroll
        for (int i = 0; i < WF4 / 256; ++i)
            wv[i] = *(const float4*)&wsrc[(tid + i * 256) * 4];
#pragma unroll
        for (int i = 0; i < 4; ++i) {
            int f = tid + i * 256;
            int m = f >> 3, c = f & 7;
            sAT[(4 * c + 0) * SA + m] = av[i].x;
            sAT[(4 * c + 1) * SA + m] = av[i].y;
            sAT[(4 * c + 2) * SA + m] = av[i].z;
            sAT[(4 * c + 3) * SA + m] = av[i].w;
        }
#pragma unroll
        for (int i = 0; i < WF4 / 256; ++i)
            *(float4*)&sW[(tid + i * 256) * 4] = wv[i];
        __syncthreads();

#pragma unroll 4
        for (int k = 0; k < BK; ++k) {
            float a[TM];
            float4 a0 = *(const float4*)&sAT[k * SA + ty * TM];
            a[0] = a0.x; a[1] = a0.y; a[2] = a0.z; a[3] = a0.w;
            if (TM == 8) {
                float4 a1 = *(const float4*)&sAT[k * SA + ty * TM + 4];
                a[4] = a1.x; a[5] = a1.y; a[6] = a1.z; a[7] = a1.w;
            }
            float4 b0 = *(const float4*)&sW[k * BN + tx * 4];
            float4 b1 = *(const float4*)&sW[k * BN + BN / 2 + tx * 4];
#pragma unroll
            for (int i = 0; i < TM; ++i) {
                acc[i][0] += a[i] * b0.x;
                acc[i][1] += a[i] * b0.y;
                acc[i][2] += a[i] * b0.z;
                acc[i][3] += a[i] * b0.w;
                acc[i][4] += a[i] * b1.x;
                acc[i][5] += a[i] * b1.y;
                acc[i][6] += a[i] * b1.z;
                acc[i][7] += a[i] * b1.w;
            }
        }
        __syncthreads();
    }

#pragma unroll
    for (int i = 0; i < TM; ++i) {
        int row = row0 + ty * TM + i;
        if (row < NN) {
            float dv = dinv[row];
            float4 o0, o1;
            o0.x = acc[i][0] * dv; o0.y = acc[i][1] * dv;
            o0.z = acc[i][2] * dv; o0.w = acc[i][3] * dv;
            o1.x = acc[i][4] * dv; o1.y = acc[i][5] * dv;
            o1.z = acc[i][6] * dv; o1.w = acc[i][7] * dv;
            *(float4*)&out[(size_t)row * BN + tx * 4] = o0;
            *(float4*)&out[(size_t)row * BN + BN / 2 + tx * 4] = o1;
        }
    }
}

// z[n] = relu(dinv[n] * (sum_{e: dst=n} hs[src_e] + hs[n]) + b)
// One wave per node. D=128: float2/lane -> the whole 512B row in ONE vmem
// instruction; unroll x4 -> 4 rows in flight per wave (latency hiding).
template <int D>
__global__ __launch_bounds__(256) void k_agg(
    const float* __restrict__ hs, const float* __restrict__ dinv,
    const int* __restrict__ off, const int* __restrict__ csrc,
    const float* __restrict__ bias, float* __restrict__ z) {
    int node = blockIdx.x * 4 + (threadIdx.x >> 6);
    if (node >= NN) return;
    int lane = threadIdx.x & 63;
    int s = off[node], e = off[node + 1];
    if (D == 128) {
        const float2* h2 = (const float2*)hs;  // row stride 64 float2
        float a0 = 0.f, a1 = 0.f;
        int j = s;
        for (; j + 4 <= e; j += 4) {
            int s0 = csrc[j], s1 = csrc[j + 1], s2 = csrc[j + 2], s3 = csrc[j + 3];
            float2 v0 = h2[(size_t)s0 * 64 + lane];
            float2 v1 = h2[(size_t)s1 * 64 + lane];
            float2 v2 = h2[(size_t)s2 * 64 + lane];
            float2 v3 = h2[(size_t)s3 * 64 + lane];
            a0 += v0.x + v1.x + v2.x + v3.x;
            a1 += v0.y + v1.y + v2.y + v3.y;
        }
        for (; j < e; ++j) {
            float2 v = h2[(size_t)csrc[j] * 64 + lane];
            a0 += v.x; a1 += v.y;
        }
        float2 vs = h2[(size_t)node * 64 + lane];  // self loop
        a0 += vs.x; a1 += vs.y;
        float dv = dinv[node];
        float2 bb = ((const float2*)bias)[lane];
        float r0 = dv * a0 + bb.x;
        float r1 = dv * a1 + bb.y;
        ((float2*)z)[(size_t)node * 64 + lane] =
            make_float2(r0 > 0.f ? r0 : 0.f, r1 > 0.f ? r1 : 0.f);
    } else {
        float a0 = 0.f;
        int j = s;
        for (; j + 4 <= e; j += 4) {
            int s0 = csrc[j], s1 = csrc[j + 1], s2 = csrc[j + 2], s3 = csrc[j + 3];
            float v0 = hs[(size_t)s0 * D + lane];
            float v1 = hs[(size_t)s1 * D + lane];
            float v2 = hs[(size_t)s2 * D + lane];
            float v3 = hs[(size_t)s3 * D + lane];
            a0 += v0 + v1 + v2 + v3;
        }
        for (; j < e; ++j) a0 += hs[(size_t)csrc[j] * D + lane];
        a0 += hs[(size_t)node * D + lane];  // self loop
        float dv = dinv[node];
        float r0 = dv * a0 + bias[lane];
        z[(size_t)node * D + lane] = r0 > 0.f ? r0 : 0.f;
    }
}

// 2 pairs per 16-lane group -> 4 float4 gathers in flight per group
__global__ __launch_bounds__(256) void k_dec(const float* __restrict__ z2,
                                             const int* __restrict__ eli,
                                             float* __restrict__ out) {
    int g = blockIdx.x * 16 + (threadIdx.x >> 4);
    int p0 = g * 2;
    if (p0 >= ND) return;
    int p1 = p0 + 1;
    int sub = threadIdx.x & 15;
    int ia0 = eli[p0], ib0 = eli[ND + p0];
    int ia1 = eli[p1], ib1 = eli[ND + p1];
    float4 va0 = *(const float4*)&z2[(size_t)ia0 * DO + sub * 4];
    float4 vb0 = *(const float4*)&z2[(size_t)ib0 * DO + sub * 4];
    float4 va1 = *(const float4*)&z2[(size_t)ia1 * DO + sub * 4];
    float4 vb1 = *(const float4*)&z2[(size_t)ib1 * DO + sub * 4];
    float v0 = va0.x * vb0.x + va0.y * vb0.y + va0.z * vb0.z + va0.w * vb0.w;
    float v1 = va1.x * vb1.x + va1.y * vb1.y + va1.z * vb1.z + va1.w * vb1.w;
#pragma unroll
    for (int o = 1; o < 16; o <<= 1) {
        v0 += __shfl_xor(v0, o);
        v1 += __shfl_xor(v1, o);
    }
    if (sub == 0) *(float2*)&out[p0] = make_float2(v0, v1);
}

extern "C" void kernel_launch(void* const* d_in, const int* in_sizes, int n_in,
                              void* d_out, int out_size, void* d_ws, size_t ws_size,
                              hipStream_t stream) {
    const float* x  = (const float*)d_in[0];
    const float* Wi = (const float*)d_in[1];
    const float* bi = (const float*)d_in[2];
    const float* Wo = (const float*)d_in[3];
    const float* bo = (const float*)d_in[4];
    const int* ei   = (const int*)d_in[5];
    const int* eli  = (const int*)d_in[6];
    float* out = (float*)d_out;

    char* ws = (char*)d_ws;
    size_t o = 0;
    auto alloc = [&](size_t bytes) -> char* {
        char* p = ws + o;
        o = (o + bytes + 255) & ~(size_t)255;
        return p;
    };
    float* dinv = (float*)alloc(NN * 4);
    int* degi   = (int*)alloc(NN * 4);
    int* off    = (int*)alloc((NN + 1) * 4);
    int* cur    = (int*)alloc(NN * 4);
    int* part   = (int*)alloc(SCAN_GRID * 4);
    int* csrc   = (int*)alloc((size_t)NE * 4);
    float* h1   = (float*)alloc((size_t)NN * DH * 4);
    float* z1   = (float*)alloc((size_t)NN * DH * 4);
    float* h2   = (float*)alloc((size_t)NN * DO * 4);
    float* z2   = (float*)alloc((size_t)NN * DO * 4);

    const int* esrc = ei;
    const int* edst = ei + NE;

    hipMemsetAsync(degi, 0, NN * 4, stream);
    hipMemsetAsync(cur, 0, NN * 4, stream);
    k_count<<<(NE + 255) / 256, 256, 0, stream>>>(edst, degi);
    k_blocksum<<<SCAN_GRID, 256, 0, stream>>>(degi, part);
    k_scanpart<<<1, 256, 0, stream>>>(part, SCAN_GRID);
    k_scanfinal<<<SCAN_GRID, 256, 0, stream>>>(degi, part, off, dinv);
    k_fill<<<(NE + 255) / 256, 256, 0, stream>>>(esrc, edst, off, cur, csrc);

    k_gemm_scale<DH><<<(NN + 127) / 128, 256, 0, stream>>>(x, Wi, dinv, h1);
    k_agg<DH><<<(NN + 3) / 4, 256, 0, stream>>>(h1, dinv, off, csrc, bi, z1);
    k_gemm_scale<DO><<<(NN + 127) / 128, 256, 0, stream>>>(z1, Wo, dinv, h2);
    k_agg<DO><<<(NN + 3) / 4, 256, 0, stream>>>(h2, dinv, off, csrc, bo, z2);

    k_dec<<<(ND + 31) / 32, 256, 0, stream>>>(z2, eli, out);
}

// Round 5
// 234.585 us; speedup vs baseline: 4.1219x; 1.2410x over previous
//
#include <hip/hip_runtime.h>

#define NN 50000
#define NE 800000
#define ND 1000000
#define DI 128
#define DH 128
#define DO 64

#define SCAN_GRID ((NN + 255) / 256)   // 196

typedef _Float16 h16;
typedef h16 h16x2 __attribute__((ext_vector_type(2)));
typedef h16 h16x4 __attribute__((ext_vector_type(4)));

__global__ void k_count(const int* __restrict__ dst, int* __restrict__ degi,
                        int* __restrict__ rank) {
    int i = blockIdx.x * blockDim.x + threadIdx.x;
    if (i < NE) rank[i] = atomicAdd(&degi[dst[i]], 1);
}

// phase 1: per-block sums of degi
__global__ __launch_bounds__(256) void k_blocksum(const int* __restrict__ degi,
                                                  int* __restrict__ part) {
    int i = blockIdx.x * 256 + threadIdx.x;
    int v = (i < NN) ? degi[i] : 0;
#pragma unroll
    for (int o = 1; o < 64; o <<= 1) v += __shfl_xor(v, o);
    __shared__ int s[4];
    if ((threadIdx.x & 63) == 0) s[threadIdx.x >> 6] = v;
    __syncthreads();
    if (threadIdx.x == 0) part[blockIdx.x] = s[0] + s[1] + s[2] + s[3];
}

// phase 2: exclusive scan of the <=256 partials (single block)
__global__ __launch_bounds__(256) void k_scanpart(int* __restrict__ part, int n) {
    int t = threadIdx.x;
    int v = (t < n) ? part[t] : 0;
    __shared__ int s[256];
    s[t] = v;
    __syncthreads();
#pragma unroll
    for (int d = 1; d < 256; d <<= 1) {
        int add = (t >= d) ? s[t - d] : 0;
        __syncthreads();
        s[t] += add;
        __syncthreads();
    }
    if (t < n) part[t] = s[t] - v;  // exclusive
}

// phase 3: block-local exclusive scan + partial offset; fuse dinv compute
__global__ __launch_bounds__(256) void k_scanfinal(const int* __restrict__ degi,
                                                   const int* __restrict__ part,
                                                   int* __restrict__ off,
                                                   float* __restrict__ dinv) {
    int b = blockIdx.x, t = threadIdx.x;
    int i = b * 256 + t;
    int v = (i < NN) ? degi[i] : 0;
    __shared__ int s[256];
    s[t] = v;
    __syncthreads();
#pragma unroll
    for (int d = 1; d < 256; d <<= 1) {
        int add = (t >= d) ? s[t - d] : 0;
        __syncthreads();
        s[t] += add;
        __syncthreads();
    }
    if (i < NN) {
        off[i] = part[b] + s[t] - v;
        dinv[i] = rsqrtf((float)v + 1.0f);  // +1 self-loop
    }
    if (i == 0) off[NN] = NE;  // total degree == edge count
}

// pure scatter, no atomics (rank captured in k_count)
__global__ void k_fill(const int* __restrict__ src, const int* __restrict__ dst,
                       const int* __restrict__ off, const int* __restrict__ rank,
                       int* __restrict__ csrc) {
    int i = blockIdx.x * blockDim.x + threadIdx.x;
    if (i < NE) csrc[off[dst[i]] + rank[i]] = src[i];
}

// out[row][:] = fp16( (A[row][:] @ W) * dinv[row] )
template <int BN>
__global__ __launch_bounds__(256) void k_gemm_scale(
    const float* __restrict__ A, const float* __restrict__ W,
    const float* __restrict__ dinv, h16* __restrict__ out) {
    constexpr int BM = 128, BK = 32, K = 128;
    constexpr int TM = (BN == 128) ? 8 : 4;
    constexpr int NTX = BN / 8;          // 16 (BN=128) or 8 (BN=64)
    constexpr int SA = 132;              // sAT row stride (floats)
    __shared__ float sAT[BK * SA];       // sAT[k][m] = A[row0+m][k0+k]
    __shared__ float sW[BK * BN];        // sW[k][n]  = W[k0+k][n]

    const int tid = threadIdx.x;
    const int row0 = blockIdx.x * BM;
    const int tx = tid & (NTX - 1);
    const int ty = tid / NTX;            // row group

    float acc[TM][8];
#pragma unroll
    for (int i = 0; i < TM; ++i)
#pragma unroll
        for (int j = 0; j < 8; ++j) acc[i][j] = 0.f;

    for (int t = 0; t < K / BK; ++t) {
        const int k0 = t * BK;
        float4 av[4];
#pragma unroll
        for (int i = 0; i < 4; ++i) {
            int f = tid + i * 256;       // float4 index in [0,1024)
            int m = f >> 3, c = f & 7;
            int gr = row0 + m;
            av[i] = (gr < NN) ? *(const float4*)&A[(size_t)gr * K + k0 + 4 * c]
                              : make_float4(0.f, 0.f, 0.f, 0.f);
        }
        constexpr int WF4 = BK * BN / 4; // 1024 or 512
        float4 wv[WF4 / 256];
        const float* wsrc = W + (size_t)k0 * BN;
#pragma unroll
        for (int i = 0; i < WF4 / 256; ++i)
            wv[i] = *(const float4*)&wsrc[(tid + i * 256) * 4];
#pragma unroll
        for (int i = 0; i < 4; ++i) {
            int f = tid + i * 256;
            int m = f >> 3, c = f & 7;
            sAT[(4 * c + 0) * SA + m] = av[i].x;
            sAT[(4 * c + 1) * SA + m] = av[i].y;
            sAT[(4 * c + 2) * SA + m] = av[i].z;
            sAT[(4 * c + 3) * SA + m] = av[i].w;
        }
#pragma unroll
        for (int i = 0; i < WF4 / 256; ++i)
            *(float4*)&sW[(tid + i * 256) * 4] = wv[i];
        __syncthreads();

#pragma unroll 4
        for (int k = 0; k < BK; ++k) {
            float a[TM];
            float4 a0 = *(const float4*)&sAT[k * SA + ty * TM];
            a[0] = a0.x; a[1] = a0.y; a[2] = a0.z; a[3] = a0.w;
            if (TM == 8) {
                float4 a1 = *(const float4*)&sAT[k * SA + ty * TM + 4];
                a[4] = a1.x; a[5] = a1.y; a[6] = a1.z; a[7] = a1.w;
            }
            float4 b0 = *(const float4*)&sW[k * BN + tx * 4];
            float4 b1 = *(const float4*)&sW[k * BN + BN / 2 + tx * 4];
#pragma unroll
            for (int i = 0; i < TM; ++i) {
                acc[i][0] += a[i] * b0.x;
                acc[i][1] += a[i] * b0.y;
                acc[i][2] += a[i] * b0.z;
                acc[i][3] += a[i] * b0.w;
                acc[i][4] += a[i] * b1.x;
                acc[i][5] += a[i] * b1.y;
                acc[i][6] += a[i] * b1.z;
                acc[i][7] += a[i] * b1.w;
            }
        }
        __syncthreads();
    }

#pragma unroll
    for (int i = 0; i < TM; ++i) {
        int row = row0 + ty * TM + i;
        if (row < NN) {
            float dv = dinv[row];
            h16x4 o0, o1;
            o0.x = (h16)(acc[i][0] * dv); o0.y = (h16)(acc[i][1] * dv);
            o0.z = (h16)(acc[i][2] * dv); o0.w = (h16)(acc[i][3] * dv);
            o1.x = (h16)(acc[i][4] * dv); o1.y = (h16)(acc[i][5] * dv);
            o1.z = (h16)(acc[i][6] * dv); o1.w = (h16)(acc[i][7] * dv);
            *(h16x4*)&out[(size_t)row * BN + tx * 4] = o0;
            *(h16x4*)&out[(size_t)row * BN + BN / 2 + tx * 4] = o1;
        }
    }
}

// z1[n] = relu(dinv[n]*(sum h1[src] + h1[n]) + b), h1 fp16 [NN][128], z1 fp32
__global__ __launch_bounds__(256) void k_agg128(
    const h16x2* __restrict__ hs, const float* __restrict__ dinv,
    const int* __restrict__ off, const int* __restrict__ csrc,
    const float* __restrict__ bias, float* __restrict__ z) {
    int node = blockIdx.x * 4 + (threadIdx.x >> 6);
    if (node >= NN) return;
    int lane = threadIdx.x & 63;
    int s = off[node], e = off[node + 1];
    float a0 = 0.f, a1 = 0.f;
    int j = s;
    for (; j + 4 <= e; j += 4) {
        int s0 = csrc[j], s1 = csrc[j + 1], s2 = csrc[j + 2], s3 = csrc[j + 3];
        h16x2 v0 = hs[(size_t)s0 * 64 + lane];
        h16x2 v1 = hs[(size_t)s1 * 64 + lane];
        h16x2 v2 = hs[(size_t)s2 * 64 + lane];
        h16x2 v3 = hs[(size_t)s3 * 64 + lane];
        a0 += (float)v0.x + (float)v1.x + (float)v2.x + (float)v3.x;
        a1 += (float)v0.y + (float)v1.y + (float)v2.y + (float)v3.y;
    }
    for (; j < e; ++j) {
        h16x2 v = hs[(size_t)csrc[j] * 64 + lane];
        a0 += (float)v.x; a1 += (float)v.y;
    }
    h16x2 vs = hs[(size_t)node * 64 + lane];  // self loop
    a0 += (float)vs.x; a1 += (float)vs.y;
    float dv = dinv[node];
    float2 bb = ((const float2*)bias)[lane];
    float r0 = dv * a0 + bb.x;
    float r1 = dv * a1 + bb.y;
    ((float2*)z)[(size_t)node * 64 + lane] =
        make_float2(r0 > 0.f ? r0 : 0.f, r1 > 0.f ? r1 : 0.f);
}

// z2[n] = relu(dinv[n]*(sum h2[src] + h2[n]) + b), h2 fp16 [NN][64], z2 fp32.
// Row = 32 h16x2; half-wave per edge -> 2 edges/iter, x4 unroll -> 8 in flight.
__global__ __launch_bounds__(256) void k_agg64(
    const h16x2* __restrict__ hs, const float* __restrict__ dinv,
    const int* __restrict__ off, const int* __restrict__ csrc,
    const float* __restrict__ bias, float* __restrict__ z) {
    int node = blockIdx.x * 4 + (threadIdx.x >> 6);
    if (node >= NN) return;
    int lane = threadIdx.x & 63;
    int hid = lane >> 5, col = lane & 31;
    int s = off[node], e = off[node + 1];
    float a0 = 0.f, a1 = 0.f;
    int j = s;
    for (; j + 8 <= e; j += 8) {
        int i0 = csrc[j + hid], i1 = csrc[j + 2 + hid];
        int i2 = csrc[j + 4 + hid], i3 = csrc[j + 6 + hid];
        h16x2 v0 = hs[(size_t)i0 * 32 + col];
        h16x2 v1 = hs[(size_t)i1 * 32 + col];
        h16x2 v2 = hs[(size_t)i2 * 32 + col];
        h16x2 v3 = hs[(size_t)i3 * 32 + col];
        a0 += (float)v0.x + (float)v1.x + (float)v2.x + (float)v3.x;
        a1 += (float)v0.y + (float)v1.y + (float)v2.y + (float)v3.y;
    }
    for (; j < e; j += 2) {
        if (j + hid < e) {
            h16x2 v = hs[(size_t)csrc[j + hid] * 32 + col];
            a0 += (float)v.x; a1 += (float)v.y;
        }
    }
    if (hid == 0) {  // self loop, count once
        h16x2 v = hs[(size_t)node * 32 + col];
        a0 += (float)v.x; a1 += (float)v.y;
    }
    a0 += __shfl_xor(a0, 32);
    a1 += __shfl_xor(a1, 32);
    if (hid == 0) {
        float dv = dinv[node];
        float2 bb = ((const float2*)bias)[col];
        float r0 = dv * a0 + bb.x;
        float r1 = dv * a1 + bb.y;
        ((float2*)z)[(size_t)node * 32 + col] =
            make_float2(r0 > 0.f ? r0 : 0.f, r1 > 0.f ? r1 : 0.f);
    }
}

// 2 pairs per 16-lane group -> 4 float4 gathers in flight per group
__global__ __launch_bounds__(256) void k_dec(const float* __restrict__ z2,
                                             const int* __restrict__ eli,
                                             float* __restrict__ out) {
    int g = blockIdx.x * 16 + (threadIdx.x >> 4);
    int p0 = g * 2;
    if (p0 >= ND) return;
    int p1 = p0 + 1;
    int sub = threadIdx.x & 15;
    int ia0 = eli[p0], ib0 = eli[ND + p0];
    int ia1 = eli[p1], ib1 = eli[ND + p1];
    float4 va0 = *(const float4*)&z2[(size_t)ia0 * DO + sub * 4];
    float4 vb0 = *(const float4*)&z2[(size_t)ib0 * DO + sub * 4];
    float4 va1 = *(const float4*)&z2[(size_t)ia1 * DO + sub * 4];
    float4 vb1 = *(const float4*)&z2[(size_t)ib1 * DO + sub * 4];
    float v0 = va0.x * vb0.x + va0.y * vb0.y + va0.z * vb0.z + va0.w * vb0.w;
    float v1 = va1.x * vb1.x + va1.y * vb1.y + va1.z * vb1.z + va1.w * vb1.w;
#pragma unroll
    for (int o = 1; o < 16; o <<= 1) {
        v0 += __shfl_xor(v0, o);
        v1 += __shfl_xor(v1, o);
    }
    if (sub == 0) *(float2*)&out[p0] = make_float2(v0, v1);
}

extern "C" void kernel_launch(void* const* d_in, const int* in_sizes, int n_in,
                              void* d_out, int out_size, void* d_ws, size_t ws_size,
                              hipStream_t stream) {
    const float* x  = (const float*)d_in[0];
    const float* Wi = (const float*)d_in[1];
    const float* bi = (const float*)d_in[2];
    const float* Wo = (const float*)d_in[3];
    const float* bo = (const float*)d_in[4];
    const int* ei   = (const int*)d_in[5];
    const int* eli  = (const int*)d_in[6];
    float* out = (float*)d_out;

    char* ws = (char*)d_ws;
    size_t o = 0;
    auto alloc = [&](size_t bytes) -> char* {
        char* p = ws + o;
        o = (o + bytes + 255) & ~(size_t)255;
        return p;
    };
    float* dinv = (float*)alloc(NN * 4);
    int* degi   = (int*)alloc(NN * 4);
    int* off    = (int*)alloc((NN + 1) * 4);
    int* part   = (int*)alloc(SCAN_GRID * 4);
    int* rank   = (int*)alloc((size_t)NE * 4);
    int* csrc   = (int*)alloc((size_t)NE * 4);
    h16* h1     = (h16*)alloc((size_t)NN * DH * 2);
    float* z1   = (float*)alloc((size_t)NN * DH * 4);
    h16* h2     = (h16*)alloc((size_t)NN * DO * 2);
    float* z2   = (float*)alloc((size_t)NN * DO * 4);

    const int* esrc = ei;
    const int* edst = ei + NE;

    hipMemsetAsync(degi, 0, NN * 4, stream);
    k_count<<<(NE + 255) / 256, 256, 0, stream>>>(edst, degi, rank);
    k_blocksum<<<SCAN_GRID, 256, 0, stream>>>(degi, part);
    k_scanpart<<<1, 256, 0, stream>>>(part, SCAN_GRID);
    k_scanfinal<<<SCAN_GRID, 256, 0, stream>>>(degi, part, off, dinv);
    k_fill<<<(NE + 255) / 256, 256, 0, stream>>>(esrc, edst, off, rank, csrc);

    k_gemm_scale<DH><<<(NN + 127) / 128, 256, 0, stream>>>(x, Wi, dinv, h1);
    k_agg128<<<(NN + 3) / 4, 256, 0, stream>>>((const h16x2*)h1, dinv, off, csrc, bi, z1);
    k_gemm_scale<DO><<<(NN + 127) / 128, 256, 0, stream>>>(z1, Wo, dinv, h2);
    k_agg64<<<(NN + 3) / 4, 256, 0, stream>>>((const h16x2*)h2, dinv, off, csrc, bo, z2);

    k_dec<<<(ND + 31) / 32, 256, 0, stream>>>(z2, eli, out);
}

// Round 6
// 200.176 us; speedup vs baseline: 4.8304x; 1.1719x over previous
//
#include <hip/hip_runtime.h>

#define NN 50000
#define NE 800000
#define ND 1000000
#define DI 128
#define DH 128
#define DO 64

#define SCAN_GRID ((NN + 255) / 256)   // 196

typedef _Float16 h16;
typedef h16 h16x2 __attribute__((ext_vector_type(2)));
typedef h16 h16x4 __attribute__((ext_vector_type(4)));

__global__ void k_count(const int* __restrict__ dst, int* __restrict__ degi,
                        int* __restrict__ rank) {
    int i = blockIdx.x * blockDim.x + threadIdx.x;
    if (i < NE) rank[i] = atomicAdd(&degi[dst[i]], 1);
}

// phase 1: per-block sums of degi
__global__ __launch_bounds__(256) void k_blocksum(const int* __restrict__ degi,
                                                  int* __restrict__ part) {
    int i = blockIdx.x * 256 + threadIdx.x;
    int v = (i < NN) ? degi[i] : 0;
#pragma unroll
    for (int o = 1; o < 64; o <<= 1) v += __shfl_xor(v, o);
    __shared__ int s[4];
    if ((threadIdx.x & 63) == 0) s[threadIdx.x >> 6] = v;
    __syncthreads();
    if (threadIdx.x == 0) part[blockIdx.x] = s[0] + s[1] + s[2] + s[3];
}

// phase 2: exclusive scan of the <=256 partials (single block)
__global__ __launch_bounds__(256) void k_scanpart(int* __restrict__ part, int n) {
    int t = threadIdx.x;
    int v = (t < n) ? part[t] : 0;
    __shared__ int s[256];
    s[t] = v;
    __syncthreads();
#pragma unroll
    for (int d = 1; d < 256; d <<= 1) {
        int add = (t >= d) ? s[t - d] : 0;
        __syncthreads();
        s[t] += add;
        __syncthreads();
    }
    if (t < n) part[t] = s[t] - v;  // exclusive
}

// phase 3: block-local exclusive scan + partial offset; fuse dinv compute
__global__ __launch_bounds__(256) void k_scanfinal(const int* __restrict__ degi,
                                                   const int* __restrict__ part,
                                                   int* __restrict__ off,
                                                   float* __restrict__ dinv) {
    int b = blockIdx.x, t = threadIdx.x;
    int i = b * 256 + t;
    int v = (i < NN) ? degi[i] : 0;
    __shared__ int s[256];
    s[t] = v;
    __syncthreads();
#pragma unroll
    for (int d = 1; d < 256; d <<= 1) {
        int add = (t >= d) ? s[t - d] : 0;
        __syncthreads();
        s[t] += add;
        __syncthreads();
    }
    if (i < NN) {
        off[i] = part[b] + s[t] - v;
        dinv[i] = rsqrtf((float)v + 1.0f);  // +1 self-loop
    }
    if (i == 0) off[NN] = NE;  // total degree == edge count
}

// pure scatter, no atomics (rank captured in k_count)
__global__ void k_fill(const int* __restrict__ src, const int* __restrict__ dst,
                       const int* __restrict__ off, const int* __restrict__ rank,
                       int* __restrict__ csrc) {
    int i = blockIdx.x * blockDim.x + threadIdx.x;
    if (i < NE) csrc[off[dst[i]] + rank[i]] = src[i];
}

// out[row][:] = fp16( (A[row][:] @ W) * dinv[row] )
template <int BN>
__global__ __launch_bounds__(256) void k_gemm_scale(
    const float* __restrict__ A, const float* __restrict__ W,
    const float* __restrict__ dinv, h16* __restrict__ out) {
    constexpr int BM = 128, BK = 32, K = 128;
    constexpr int TM = (BN == 128) ? 8 : 4;
    constexpr int NTX = BN / 8;          // 16 (BN=128) or 8 (BN=64)
    constexpr int SA = 132;              // sAT row stride (floats)
    __shared__ float sAT[BK * SA];       // sAT[k][m] = A[row0+m][k0+k]
    __shared__ float sW[BK * BN];        // sW[k][n]  = W[k0+k][n]

    const int tid = threadIdx.x;
    const int row0 = blockIdx.x * BM;
    const int tx = tid & (NTX - 1);
    const int ty = tid / NTX;            // row group

    float acc[TM][8];
#pragma unroll
    for (int i = 0; i < TM; ++i)
#pragma unroll
        for (int j = 0; j < 8; ++j) acc[i][j] = 0.f;

    for (int t = 0; t < K / BK; ++t) {
        const int k0 = t * BK;
        float4 av[4];
#pragma unroll
        for (int i = 0; i < 4; ++i) {
            int f = tid + i * 256;       // float4 index in [0,1024)
            int m = f >> 3, c = f & 7;
            int gr = row0 + m;
            av[i] = (gr < NN) ? *(const float4*)&A[(size_t)gr * K + k0 + 4 * c]
                              : make_float4(0.f, 0.f, 0.f, 0.f);
        }
        constexpr int WF4 = BK * BN / 4; // 1024 or 512
        float4 wv[WF4 / 256];
        const float* wsrc = W + (size_t)k0 * BN;
#pragma unroll
        for (int i = 0; i < WF4 / 256; ++i)
            wv[i] = *(const float4*)&wsrc[(tid + i * 256) * 4];
#pragma unroll
        for (int i = 0; i < 4; ++i) {
            int f = tid + i * 256;
            int m = f >> 3, c = f & 7;
            sAT[(4 * c + 0) * SA + m] = av[i].x;
            sAT[(4 * c + 1) * SA + m] = av[i].y;
            sAT[(4 * c + 2) * SA + m] = av[i].z;
            sAT[(4 * c + 3) * SA + m] = av[i].w;
        }
#pragma unroll
        for (int i = 0; i < WF4 / 256; ++i)
            *(float4*)&sW[(tid + i * 256) * 4] = wv[i];
        __syncthreads();

#pragma unroll 4
        for (int k = 0; k < BK; ++k) {
            float a[TM];
            float4 a0 = *(const float4*)&sAT[k * SA + ty * TM];
            a[0] = a0.x; a[1] = a0.y; a[2] = a0.z; a[3] = a0.w;
            if (TM == 8) {
                float4 a1 = *(const float4*)&sAT[k * SA + ty * TM + 4];
                a[4] = a1.x; a[5] = a1.y; a[6] = a1.z; a[7] = a1.w;
            }
            float4 b0 = *(const float4*)&sW[k * BN + tx * 4];
            float4 b1 = *(const float4*)&sW[k * BN + BN / 2 + tx * 4];
#pragma unroll
            for (int i = 0; i < TM; ++i) {
                acc[i][0] += a[i] * b0.x;
                acc[i][1] += a[i] * b0.y;
                acc[i][2] += a[i] * b0.z;
                acc[i][3] += a[i] * b0.w;
                acc[i][4] += a[i] * b1.x;
                acc[i][5] += a[i] * b1.y;
                acc[i][6] += a[i] * b1.z;
                acc[i][7] += a[i] * b1.w;
            }
        }
        __syncthreads();
    }

#pragma unroll
    for (int i = 0; i < TM; ++i) {
        int row = row0 + ty * TM + i;
        if (row < NN) {
            float dv = dinv[row];
            h16x4 o0, o1;
            o0.x = (h16)(acc[i][0] * dv); o0.y = (h16)(acc[i][1] * dv);
            o0.z = (h16)(acc[i][2] * dv); o0.w = (h16)(acc[i][3] * dv);
            o1.x = (h16)(acc[i][4] * dv); o1.y = (h16)(acc[i][5] * dv);
            o1.z = (h16)(acc[i][6] * dv); o1.w = (h16)(acc[i][7] * dv);
            *(h16x4*)&out[(size_t)row * BN + tx * 4] = o0;
            *(h16x4*)&out[(size_t)row * BN + BN / 2 + tx * 4] = o1;
        }
    }
}

// z1[n] = relu(dinv[n]*(sum h1[src] + h1[n]) + b), h1 fp16 [NN][128], z1 fp32
__global__ __launch_bounds__(256) void k_agg128(
    const h16x2* __restrict__ hs, const float* __restrict__ dinv,
    const int* __restrict__ off, const int* __restrict__ csrc,
    const float* __restrict__ bias, float* __restrict__ z) {
    int node = blockIdx.x * 4 + (threadIdx.x >> 6);
    if (node >= NN) return;
    int lane = threadIdx.x & 63;
    int s = off[node], e = off[node + 1];
    float a0 = 0.f, a1 = 0.f;
    int j = s;
    for (; j + 8 <= e; j += 8) {
        int s0 = csrc[j],     s1 = csrc[j + 1], s2 = csrc[j + 2], s3 = csrc[j + 3];
        int s4 = csrc[j + 4], s5 = csrc[j + 5], s6 = csrc[j + 6], s7 = csrc[j + 7];
        h16x2 v0 = hs[(size_t)s0 * 64 + lane];
        h16x2 v1 = hs[(size_t)s1 * 64 + lane];
        h16x2 v2 = hs[(size_t)s2 * 64 + lane];
        h16x2 v3 = hs[(size_t)s3 * 64 + lane];
        h16x2 v4 = hs[(size_t)s4 * 64 + lane];
        h16x2 v5 = hs[(size_t)s5 * 64 + lane];
        h16x2 v6 = hs[(size_t)s6 * 64 + lane];
        h16x2 v7 = hs[(size_t)s7 * 64 + lane];
        a0 += ((float)v0.x + (float)v1.x + (float)v2.x + (float)v3.x) +
              ((float)v4.x + (float)v5.x + (float)v6.x + (float)v7.x);
        a1 += ((float)v0.y + (float)v1.y + (float)v2.y + (float)v3.y) +
              ((float)v4.y + (float)v5.y + (float)v6.y + (float)v7.y);
    }
    for (; j + 4 <= e; j += 4) {
        int s0 = csrc[j], s1 = csrc[j + 1], s2 = csrc[j + 2], s3 = csrc[j + 3];
        h16x2 v0 = hs[(size_t)s0 * 64 + lane];
        h16x2 v1 = hs[(size_t)s1 * 64 + lane];
        h16x2 v2 = hs[(size_t)s2 * 64 + lane];
        h16x2 v3 = hs[(size_t)s3 * 64 + lane];
        a0 += (float)v0.x + (float)v1.x + (float)v2.x + (float)v3.x;
        a1 += (float)v0.y + (float)v1.y + (float)v2.y + (float)v3.y;
    }
    for (; j < e; ++j) {
        h16x2 v = hs[(size_t)csrc[j] * 64 + lane];
        a0 += (float)v.x; a1 += (float)v.y;
    }
    h16x2 vs = hs[(size_t)node * 64 + lane];  // self loop
    a0 += (float)vs.x; a1 += (float)vs.y;
    float dv = dinv[node];
    float2 bb = ((const float2*)bias)[lane];
    float r0 = dv * a0 + bb.x;
    float r1 = dv * a1 + bb.y;
    ((float2*)z)[(size_t)node * 64 + lane] =
        make_float2(r0 > 0.f ? r0 : 0.f, r1 > 0.f ? r1 : 0.f);
}

// z2[n] = fp16(relu(dinv[n]*(sum h2[src] + h2[n]) + b)), h2 fp16 [NN][64]
__global__ __launch_bounds__(256) void k_agg64(
    const h16x2* __restrict__ hs, const float* __restrict__ dinv,
    const int* __restrict__ off, const int* __restrict__ csrc,
    const float* __restrict__ bias, h16x2* __restrict__ z) {
    int node = blockIdx.x * 4 + (threadIdx.x >> 6);
    if (node >= NN) return;
    int lane = threadIdx.x & 63;
    int hid = lane >> 5, col = lane & 31;
    int s = off[node], e = off[node + 1];
    float a0 = 0.f, a1 = 0.f;
    int j = s;
    for (; j + 8 <= e; j += 8) {
        int i0 = csrc[j + hid], i1 = csrc[j + 2 + hid];
        int i2 = csrc[j + 4 + hid], i3 = csrc[j + 6 + hid];
        h16x2 v0 = hs[(size_t)i0 * 32 + col];
        h16x2 v1 = hs[(size_t)i1 * 32 + col];
        h16x2 v2 = hs[(size_t)i2 * 32 + col];
        h16x2 v3 = hs[(size_t)i3 * 32 + col];
        a0 += (float)v0.x + (float)v1.x + (float)v2.x + (float)v3.x;
        a1 += (float)v0.y + (float)v1.y + (float)v2.y + (float)v3.y;
    }
    for (; j < e; j += 2) {
        if (j + hid < e) {
            h16x2 v = hs[(size_t)csrc[j + hid] * 32 + col];
            a0 += (float)v.x; a1 += (float)v.y;
        }
    }
    if (hid == 0) {  // self loop, count once
        h16x2 v = hs[(size_t)node * 32 + col];
        a0 += (float)v.x; a1 += (float)v.y;
    }
    a0 += __shfl_xor(a0, 32);
    a1 += __shfl_xor(a1, 32);
    if (hid == 0) {
        float dv = dinv[node];
        float2 bb = ((const float2*)bias)[col];
        float r0 = dv * a0 + bb.x;
        float r1 = dv * a1 + bb.y;
        h16x2 o;
        o.x = (h16)(r0 > 0.f ? r0 : 0.f);
        o.y = (h16)(r1 > 0.f ? r1 : 0.f);
        z[(size_t)node * 32 + col] = o;
    }
}

// 4 pairs per 16-lane group -> 8 gathers (128B rows) in flight; float4 store
__global__ __launch_bounds__(256) void k_dec(const h16* __restrict__ z2,
                                             const int* __restrict__ eli,
                                             float* __restrict__ out) {
    int g = blockIdx.x * 16 + (threadIdx.x >> 4);
    int p0 = g * 4;
    if (p0 >= ND) return;
    int sub = threadIdx.x & 15;
    float v[4];
#pragma unroll
    for (int q = 0; q < 4; ++q) {
        int ia = eli[p0 + q];
        int ib = eli[ND + p0 + q];
        h16x4 va = *(const h16x4*)&z2[(size_t)ia * DO + sub * 4];
        h16x4 vb = *(const h16x4*)&z2[(size_t)ib * DO + sub * 4];
        v[q] = (float)va.x * (float)vb.x + (float)va.y * (float)vb.y +
               (float)va.z * (float)vb.z + (float)va.w * (float)vb.w;
    }
#pragma unroll
    for (int o = 1; o < 16; o <<= 1) {
#pragma unroll
        for (int q = 0; q < 4; ++q) v[q] += __shfl_xor(v[q], o);
    }
    if (sub == 0) *(float4*)&out[p0] = make_float4(v[0], v[1], v[2], v[3]);
}

extern "C" void kernel_launch(void* const* d_in, const int* in_sizes, int n_in,
                              void* d_out, int out_size, void* d_ws, size_t ws_size,
                              hipStream_t stream) {
    const float* x  = (const float*)d_in[0];
    const float* Wi = (const float*)d_in[1];
    const float* bi = (const float*)d_in[2];
    const float* Wo = (const float*)d_in[3];
    const float* bo = (const float*)d_in[4];
    const int* ei   = (const int*)d_in[5];
    const int* eli  = (const int*)d_in[6];
    float* out = (float*)d_out;

    char* ws = (char*)d_ws;
    size_t o = 0;
    auto alloc = [&](size_t bytes) -> char* {
        char* p = ws + o;
        o = (o + bytes + 255) & ~(size_t)255;
        return p;
    };
    float* dinv = (float*)alloc(NN * 4);
    int* degi   = (int*)alloc(NN * 4);
    int* off    = (int*)alloc((NN + 1) * 4);
    int* part   = (int*)alloc(SCAN_GRID * 4);
    int* rank   = (int*)alloc((size_t)NE * 4);
    int* csrc   = (int*)alloc((size_t)NE * 4);
    h16* h1     = (h16*)alloc((size_t)NN * DH * 2);
    float* z1   = (float*)alloc((size_t)NN * DH * 4);
    h16* h2     = (h16*)alloc((size_t)NN * DO * 2);
    h16* z2     = (h16*)alloc((size_t)NN * DO * 2);

    const int* esrc = ei;
    const int* edst = ei + NE;

    hipMemsetAsync(degi, 0, NN * 4, stream);
    k_count<<<(NE + 255) / 256, 256, 0, stream>>>(edst, degi, rank);
    k_blocksum<<<SCAN_GRID, 256, 0, stream>>>(degi, part);
    k_scanpart<<<1, 256, 0, stream>>>(part, SCAN_GRID);
    k_scanfinal<<<SCAN_GRID, 256, 0, stream>>>(degi, part, off, dinv);
    k_fill<<<(NE + 255) / 256, 256, 0, stream>>>(esrc, edst, off, rank, csrc);

    k_gemm_scale<DH><<<(NN + 127) / 128, 256, 0, stream>>>(x, Wi, dinv, h1);
    k_agg128<<<(NN + 3) / 4, 256, 0, stream>>>((const h16x2*)h1, dinv, off, csrc, bi, z1);
    k_gemm_scale<DO><<<(NN + 127) / 128, 256, 0, stream>>>(z1, Wo, dinv, h2);
    k_agg64<<<(NN + 3) / 4, 256, 0, stream>>>((const h16x2*)h2, dinv, off, csrc, bo, (h16x2*)z2);

    k_dec<<<(ND + 63) / 64, 256, 0, stream>>>(z2, eli, out);
}

// Round 7
// 166.463 us; speedup vs baseline: 5.8087x; 1.2025x over previous
//
#include <hip/hip_runtime.h>

#define NN 50000
#define NE 800000
#define ND 1000000
#define DI 128
#define DH 128
#define DO 64

#define SCAN_GRID ((NN + 255) / 256)     // 196
#define GB1 ((NN + 127) / 128)           // 391 gemm1 blocks
#define CB ((NE + 255) / 256)            // 3125 count blocks
#define SB ((NN * DH / 8 + 255) / 256)   // 3125 scale blocks

typedef _Float16 h16;
typedef h16 h16x2 __attribute__((ext_vector_type(2)));
typedef h16 h16x4 __attribute__((ext_vector_type(4)));
typedef h16 h16x8 __attribute__((ext_vector_type(8)));

// ---------------- GEMM body (shared by gemm1-fused and gemm2) ----------------
// out[row][:] = (A[row][:] @ W) * (SCALE ? dinv[row] : 1), fp16 output
template <int BN, bool SCALE>
__device__ __forceinline__ void gemm_body(
    const float* __restrict__ A, const float* __restrict__ W,
    const float* __restrict__ dinv, h16* __restrict__ out,
    int bx, float* sAT, float* sW) {
    constexpr int BK = 32, K = 128;
    constexpr int TM = (BN == 128) ? 8 : 4;
    constexpr int NTX = BN / 8;          // 16 (BN=128) or 8 (BN=64)
    constexpr int SA = 132;              // sAT row stride (floats)

    const int tid = threadIdx.x;
    const int row0 = bx * 128;
    const int tx = tid & (NTX - 1);
    const int ty = tid / NTX;

    float acc[TM][8];
#pragma unroll
    for (int i = 0; i < TM; ++i)
#pragma unroll
        for (int j = 0; j < 8; ++j) acc[i][j] = 0.f;

    for (int t = 0; t < K / BK; ++t) {
        const int k0 = t * BK;
        float4 av[4];
#pragma unroll
        for (int i = 0; i < 4; ++i) {
            int f = tid + i * 256;       // float4 index in [0,1024)
            int m = f >> 3, c = f & 7;
            int gr = row0 + m;
            av[i] = (gr < NN) ? *(const float4*)&A[(size_t)gr * K + k0 + 4 * c]
                              : make_float4(0.f, 0.f, 0.f, 0.f);
        }
        constexpr int WF4 = BK * BN / 4; // 1024 or 512
        float4 wv[WF4 / 256];
        const float* wsrc = W + (size_t)k0 * BN;
#pragma unroll
        for (int i = 0; i < WF4 / 256; ++i)
            wv[i] = *(const float4*)&wsrc[(tid + i * 256) * 4];
#pragma unroll
        for (int i = 0; i < 4; ++i) {
            int f = tid + i * 256;
            int m = f >> 3, c = f & 7;
            sAT[(4 * c + 0) * SA + m] = av[i].x;
            sAT[(4 * c + 1) * SA + m] = av[i].y;
            sAT[(4 * c + 2) * SA + m] = av[i].z;
            sAT[(4 * c + 3) * SA + m] = av[i].w;
        }
#pragma unroll
        for (int i = 0; i < WF4 / 256; ++i)
            *(float4*)&sW[(tid + i * 256) * 4] = wv[i];
        __syncthreads();

#pragma unroll 4
        for (int k = 0; k < BK; ++k) {
            float a[TM];
            float4 a0 = *(const float4*)&sAT[k * SA + ty * TM];
            a[0] = a0.x; a[1] = a0.y; a[2] = a0.z; a[3] = a0.w;
            if (TM == 8) {
                float4 a1 = *(const float4*)&sAT[k * SA + ty * TM + 4];
                a[4] = a1.x; a[5] = a1.y; a[6] = a1.z; a[7] = a1.w;
            }
            float4 b0 = *(const float4*)&sW[k * BN + tx * 4];
            float4 b1 = *(const float4*)&sW[k * BN + BN / 2 + tx * 4];
#pragma unroll
            for (int i = 0; i < TM; ++i) {
                acc[i][0] += a[i] * b0.x;
                acc[i][1] += a[i] * b0.y;
                acc[i][2] += a[i] * b0.z;
                acc[i][3] += a[i] * b0.w;
                acc[i][4] += a[i] * b1.x;
                acc[i][5] += a[i] * b1.y;
                acc[i][6] += a[i] * b1.z;
                acc[i][7] += a[i] * b1.w;
            }
        }
        __syncthreads();
    }

#pragma unroll
    for (int i = 0; i < TM; ++i) {
        int row = row0 + ty * TM + i;
        if (row < NN) {
            float dv = SCALE ? dinv[row] : 1.0f;
            h16x4 o0, o1;
            o0.x = (h16)(acc[i][0] * dv); o0.y = (h16)(acc[i][1] * dv);
            o0.z = (h16)(acc[i][2] * dv); o0.w = (h16)(acc[i][3] * dv);
            o1.x = (h16)(acc[i][4] * dv); o1.y = (h16)(acc[i][5] * dv);
            o1.z = (h16)(acc[i][6] * dv); o1.w = (h16)(acc[i][7] * dv);
            *(h16x4*)&out[(size_t)row * BN + tx * 4] = o0;
            *(h16x4*)&out[(size_t)row * BN + BN / 2 + tx * 4] = o1;
        }
    }
}

// K1: gemm1 (unscaled) blocks || degree-count blocks — independent work
__global__ __launch_bounds__(256) void k_gemm1_count(
    const float* __restrict__ x, const float* __restrict__ Wi,
    h16* __restrict__ h1, const int* __restrict__ edst,
    int* __restrict__ degi, int* __restrict__ rank) {
    __shared__ float sAT[32 * 132];
    __shared__ float sW[32 * 128];
    if (blockIdx.x < GB1) {
        gemm_body<128, false>(x, Wi, nullptr, h1, blockIdx.x, sAT, sW);
    } else {
        int i = (blockIdx.x - GB1) * 256 + threadIdx.x;
        if (i < NE) rank[i] = atomicAdd(&degi[edst[i]], 1);
    }
}

__global__ __launch_bounds__(256) void k_gemm2(
    const float* __restrict__ A, const float* __restrict__ W,
    const float* __restrict__ dinv, h16* __restrict__ out) {
    __shared__ float sAT[32 * 132];
    __shared__ float sW[32 * 64];
    gemm_body<64, true>(A, W, dinv, out, blockIdx.x, sAT, sW);
}

// phase 1: per-block sums of degi
__global__ __launch_bounds__(256) void k_blocksum(const int* __restrict__ degi,
                                                  int* __restrict__ part) {
    int i = blockIdx.x * 256 + threadIdx.x;
    int v = (i < NN) ? degi[i] : 0;
#pragma unroll
    for (int o = 1; o < 64; o <<= 1) v += __shfl_xor(v, o);
    __shared__ int s[4];
    if ((threadIdx.x & 63) == 0) s[threadIdx.x >> 6] = v;
    __syncthreads();
    if (threadIdx.x == 0) part[blockIdx.x] = s[0] + s[1] + s[2] + s[3];
}

// phase 2: exclusive scan of the <=256 partials (single block)
__global__ __launch_bounds__(256) void k_scanpart(int* __restrict__ part, int n) {
    int t = threadIdx.x;
    int v = (t < n) ? part[t] : 0;
    __shared__ int s[256];
    s[t] = v;
    __syncthreads();
#pragma unroll
    for (int d = 1; d < 256; d <<= 1) {
        int add = (t >= d) ? s[t - d] : 0;
        __syncthreads();
        s[t] += add;
        __syncthreads();
    }
    if (t < n) part[t] = s[t] - v;  // exclusive
}

// phase 3: block-local exclusive scan + partial offset; fuse dinv compute
__global__ __launch_bounds__(256) void k_scanfinal(const int* __restrict__ degi,
                                                   const int* __restrict__ part,
                                                   int* __restrict__ off,
                                                   float* __restrict__ dinv) {
    int b = blockIdx.x, t = threadIdx.x;
    int i = b * 256 + t;
    int v = (i < NN) ? degi[i] : 0;
    __shared__ int s[256];
    s[t] = v;
    __syncthreads();
#pragma unroll
    for (int d = 1; d < 256; d <<= 1) {
        int add = (t >= d) ? s[t - d] : 0;
        __syncthreads();
        s[t] += add;
        __syncthreads();
    }
    if (i < NN) {
        off[i] = part[b] + s[t] - v;
        dinv[i] = rsqrtf((float)v + 1.0f);  // +1 self-loop
    }
    if (i == 0) off[NN] = NE;  // total degree == edge count
}

// K5: CSR fill (pure scatter) || h1 *= dinv[row] scale — independent work
__global__ __launch_bounds__(256) void k_fill_scale(
    const int* __restrict__ src, const int* __restrict__ dst,
    const int* __restrict__ off, const int* __restrict__ rank,
    int* __restrict__ csrc, h16* __restrict__ h1,
    const float* __restrict__ dinv) {
    if (blockIdx.x < CB) {
        int i = blockIdx.x * 256 + threadIdx.x;
        if (i < NE) csrc[off[dst[i]] + rank[i]] = src[i];
    } else {
        int v = (blockIdx.x - CB) * 256 + threadIdx.x;  // h16x8 index
        if (v < NN * DH / 8) {
            int row = v >> 4;                            // 16 vec8 per row
            float dv = dinv[row];
            h16x8 h = *(h16x8*)&h1[(size_t)v * 8];
            h16x8 o;
#pragma unroll
            for (int k = 0; k < 8; ++k) o[k] = (h16)((float)h[k] * dv);
            *(h16x8*)&h1[(size_t)v * 8] = o;
        }
    }
}

// z1[n] = relu(dinv[n]*(sum h1[src] + h1[n]) + b)
// 32-lane group per node (h16x4/lane), 2 nodes/wave, no cross-lane reduce.
__global__ __launch_bounds__(256) void k_agg128(
    const h16x4* __restrict__ hs, const float* __restrict__ dinv,
    const int* __restrict__ off, const int* __restrict__ csrc,
    const float* __restrict__ bias, float* __restrict__ z) {
    int node = blockIdx.x * 8 + (threadIdx.x >> 5);
    if (node >= NN) return;
    int col = threadIdx.x & 31;              // row = 32 h16x4
    int s = off[node], e = off[node + 1];
    float a0 = 0.f, a1 = 0.f, a2 = 0.f, a3 = 0.f;
    int j = s;
    for (; j + 8 <= e; j += 8) {
        int i0 = csrc[j],     i1 = csrc[j + 1], i2 = csrc[j + 2], i3 = csrc[j + 3];
        int i4 = csrc[j + 4], i5 = csrc[j + 5], i6 = csrc[j + 6], i7 = csrc[j + 7];
        h16x4 v0 = hs[(size_t)i0 * 32 + col];
        h16x4 v1 = hs[(size_t)i1 * 32 + col];
        h16x4 v2 = hs[(size_t)i2 * 32 + col];
        h16x4 v3 = hs[(size_t)i3 * 32 + col];
        h16x4 v4 = hs[(size_t)i4 * 32 + col];
        h16x4 v5 = hs[(size_t)i5 * 32 + col];
        h16x4 v6 = hs[(size_t)i6 * 32 + col];
        h16x4 v7 = hs[(size_t)i7 * 32 + col];
        a0 += ((float)v0.x + (float)v1.x + (float)v2.x + (float)v3.x) +
              ((float)v4.x + (float)v5.x + (float)v6.x + (float)v7.x);
        a1 += ((float)v0.y + (float)v1.y + (float)v2.y + (float)v3.y) +
              ((float)v4.y + (float)v5.y + (float)v6.y + (float)v7.y);
        a2 += ((float)v0.z + (float)v1.z + (float)v2.z + (float)v3.z) +
              ((float)v4.z + (float)v5.z + (float)v6.z + (float)v7.z);
        a3 += ((float)v0.w + (float)v1.w + (float)v2.w + (float)v3.w) +
              ((float)v4.w + (float)v5.w + (float)v6.w + (float)v7.w);
    }
    for (; j < e; ++j) {
        h16x4 v = hs[(size_t)csrc[j] * 32 + col];
        a0 += (float)v.x; a1 += (float)v.y; a2 += (float)v.z; a3 += (float)v.w;
    }
    h16x4 vs = hs[(size_t)node * 32 + col];  // self loop
    a0 += (float)vs.x; a1 += (float)vs.y; a2 += (float)vs.z; a3 += (float)vs.w;
    float dv = dinv[node];
    float4 bb = ((const float4*)bias)[col];
    float4 r;
    r.x = dv * a0 + bb.x; r.y = dv * a1 + bb.y;
    r.z = dv * a2 + bb.z; r.w = dv * a3 + bb.w;
    r.x = r.x > 0.f ? r.x : 0.f; r.y = r.y > 0.f ? r.y : 0.f;
    r.z = r.z > 0.f ? r.z : 0.f; r.w = r.w > 0.f ? r.w : 0.f;
    ((float4*)z)[(size_t)node * 32 + col] = r;
}

// z2[n] = fp16(relu(dinv[n]*(sum h2[src] + h2[n]) + b))
// 16-lane group per node (h16x4/lane), 4 nodes/wave, no cross-lane reduce.
__global__ __launch_bounds__(256) void k_agg64(
    const h16x4* __restrict__ hs, const float* __restrict__ dinv,
    const int* __restrict__ off, const int* __restrict__ csrc,
    const float* __restrict__ bias, h16x4* __restrict__ z) {
    int node = blockIdx.x * 16 + (threadIdx.x >> 4);
    if (node >= NN) return;
    int col = threadIdx.x & 15;              // row = 16 h16x4
    int s = off[node], e = off[node + 1];
    float a0 = 0.f, a1 = 0.f, a2 = 0.f, a3 = 0.f;
    int j = s;
    for (; j + 8 <= e; j += 8) {
        int i0 = csrc[j],     i1 = csrc[j + 1], i2 = csrc[j + 2], i3 = csrc[j + 3];
        int i4 = csrc[j + 4], i5 = csrc[j + 5], i6 = csrc[j + 6], i7 = csrc[j + 7];
        h16x4 v0 = hs[(size_t)i0 * 16 + col];
        h16x4 v1 = hs[(size_t)i1 * 16 + col];
        h16x4 v2 = hs[(size_t)i2 * 16 + col];
        h16x4 v3 = hs[(size_t)i3 * 16 + col];
        h16x4 v4 = hs[(size_t)i4 * 16 + col];
        h16x4 v5 = hs[(size_t)i5 * 16 + col];
        h16x4 v6 = hs[(size_t)i6 * 16 + col];
        h16x4 v7 = hs[(size_t)i7 * 16 + col];
        a0 += ((float)v0.x + (float)v1.x + (float)v2.x + (float)v3.x) +
              ((float)v4.x + (float)v5.x + (float)v6.x + (float)v7.x);
        a1 += ((float)v0.y + (float)v1.y + (float)v2.y + (float)v3.y) +
              ((float)v4.y + (float)v5.y + (float)v6.y + (float)v7.y);
        a2 += ((float)v0.z + (float)v1.z + (float)v2.z + (float)v3.z) +
              ((float)v4.z + (float)v5.z + (float)v6.z + (float)v7.z);
        a3 += ((float)v0.w + (float)v1.w + (float)v2.w + (float)v3.w) +
              ((float)v4.w + (float)v5.w + (float)v6.w + (float)v7.w);
    }
    for (; j < e; ++j) {
        h16x4 v = hs[(size_t)csrc[j] * 16 + col];
        a0 += (float)v.x; a1 += (float)v.y; a2 += (float)v.z; a3 += (float)v.w;
    }
    h16x4 vs = hs[(size_t)node * 16 + col];  // self loop
    a0 += (float)vs.x; a1 += (float)vs.y; a2 += (float)vs.z; a3 += (float)vs.w;
    float dv = dinv[node];
    float4 bb = ((const float4*)bias)[col];
    float r0 = dv * a0 + bb.x, r1 = dv * a1 + bb.y;
    float r2 = dv * a2 + bb.z, r3 = dv * a3 + bb.w;
    h16x4 o;
    o.x = (h16)(r0 > 0.f ? r0 : 0.f); o.y = (h16)(r1 > 0.f ? r1 : 0.f);
    o.z = (h16)(r2 > 0.f ? r2 : 0.f); o.w = (h16)(r3 > 0.f ? r3 : 0.f);
    z[(size_t)node * 16 + col] = o;
}

// 8-lane groups, h16x8 (16B) loads, 4 pairs/group, 3-step shuffle reduce
__global__ __launch_bounds__(256) void k_dec(const h16* __restrict__ z2,
                                             const int* __restrict__ eli,
                                             float* __restrict__ out) {
    int g = blockIdx.x * 32 + (threadIdx.x >> 3);
    int p0 = g * 4;
    if (p0 >= ND) return;
    int sub = threadIdx.x & 7;
    float v[4];
#pragma unroll
    for (int q = 0; q < 4; ++q) {
        int ia = eli[p0 + q];
        int ib = eli[ND + p0 + q];
        h16x8 va = *(const h16x8*)&z2[(size_t)ia * DO + sub * 8];
        h16x8 vb = *(const h16x8*)&z2[(size_t)ib * DO + sub * 8];
        float acc = 0.f;
#pragma unroll
        for (int k = 0; k < 8; ++k) acc += (float)va[k] * (float)vb[k];
        v[q] = acc;
    }
#pragma unroll
    for (int o = 1; o < 8; o <<= 1) {
#pragma unroll
        for (int q = 0; q < 4; ++q) v[q] += __shfl_xor(v[q], o);
    }
    if (sub == 0) *(float4*)&out[p0] = make_float4(v[0], v[1], v[2], v[3]);
}

extern "C" void kernel_launch(void* const* d_in, const int* in_sizes, int n_in,
                              void* d_out, int out_size, void* d_ws, size_t ws_size,
                              hipStream_t stream) {
    const float* x  = (const float*)d_in[0];
    const float* Wi = (const float*)d_in[1];
    const float* bi = (const float*)d_in[2];
    const float* Wo = (const float*)d_in[3];
    const float* bo = (const float*)d_in[4];
    const int* ei   = (const int*)d_in[5];
    const int* eli  = (const int*)d_in[6];
    float* out = (float*)d_out;

    char* ws = (char*)d_ws;
    size_t o = 0;
    auto alloc = [&](size_t bytes) -> char* {
        char* p = ws + o;
        o = (o + bytes + 255) & ~(size_t)255;
        return p;
    };
    float* dinv = (float*)alloc(NN * 4);
    int* degi   = (int*)alloc(NN * 4);
    int* off    = (int*)alloc((NN + 1) * 4);
    int* part   = (int*)alloc(SCAN_GRID * 4);
    int* rank   = (int*)alloc((size_t)NE * 4);
    int* csrc   = (int*)alloc((size_t)NE * 4);
    h16* h1     = (h16*)alloc((size_t)NN * DH * 2);
    float* z1   = (float*)alloc((size_t)NN * DH * 4);
    h16* h2     = (h16*)alloc((size_t)NN * DO * 2);
    h16* z2     = (h16*)alloc((size_t)NN * DO * 2);

    const int* esrc = ei;
    const int* edst = ei + NE;

    hipMemsetAsync(degi, 0, NN * 4, stream);
    k_gemm1_count<<<GB1 + CB, 256, 0, stream>>>(x, Wi, h1, edst, degi, rank);
    k_blocksum<<<SCAN_GRID, 256, 0, stream>>>(degi, part);
    k_scanpart<<<1, 256, 0, stream>>>(part, SCAN_GRID);
    k_scanfinal<<<SCAN_GRID, 256, 0, stream>>>(degi, part, off, dinv);
    k_fill_scale<<<CB + SB, 256, 0, stream>>>(esrc, edst, off, rank, csrc, h1, dinv);

    k_agg128<<<(NN + 7) / 8, 256, 0, stream>>>((const h16x4*)h1, dinv, off, csrc, bi, z1);
    k_gemm2<<<(NN + 127) / 128, 256, 0, stream>>>(z1, Wo, dinv, h2);
    k_agg64<<<(NN + 15) / 16, 256, 0, stream>>>((const h16x4*)h2, dinv, off, csrc, bo, (h16x4*)z2);

    k_dec<<<(ND + 127) / 128, 256, 0, stream>>>(z2, eli, out);
}

// Round 8
// 156.362 us; speedup vs baseline: 6.1839x; 1.0646x over previous
//
#include <hip/hip_runtime.h>

#define NN 50000
#define NE 800000
#define ND 1000000
#define DH 128
#define DO 64

#define SCAN_GRID ((NN + 255) / 256)   // 196
#define CB ((NE + 255) / 256)          // 3125 count blocks
#define WTB 96                         // (128*128 + 128*64)/256 transpose blocks

typedef _Float16 h16;
typedef h16 h16x2 __attribute__((ext_vector_type(2)));
typedef h16 h16x4 __attribute__((ext_vector_type(4)));
typedef h16 h16x8 __attribute__((ext_vector_type(8)));
typedef float f32x4 __attribute__((ext_vector_type(4)));

// K1: degree count (atomic, rank capture) || W transpose+fp16 convert. No LDS.
__global__ void k_count_wt(const int* __restrict__ dst, int* __restrict__ degi,
                           int* __restrict__ rank,
                           const float* __restrict__ Wi, const float* __restrict__ Wo,
                           h16* __restrict__ WiT, h16* __restrict__ WoT) {
    if (blockIdx.x < CB) {
        int i = blockIdx.x * 256 + threadIdx.x;
        if (i < NE) rank[i] = atomicAdd(&degi[dst[i]], 1);
    } else {
        int t = (blockIdx.x - CB) * 256 + threadIdx.x;
        if (t < 128 * 128) {            // WiT[n][k] = Wi[k][n]
            int k = t >> 7, n = t & 127;
            WiT[n * 128 + k] = (h16)Wi[t];
        } else {                        // WoT[n][k] = Wo[k][n]
            int t2 = t - 128 * 128;     // < 8192
            int k = t2 >> 6, n = t2 & 63;
            WoT[n * 128 + k] = (h16)Wo[t2];
        }
    }
}

// phase 1: per-block sums of degi
__global__ __launch_bounds__(256) void k_blocksum(const int* __restrict__ degi,
                                                  int* __restrict__ part) {
    int i = blockIdx.x * 256 + threadIdx.x;
    int v = (i < NN) ? degi[i] : 0;
#pragma unroll
    for (int o = 1; o < 64; o <<= 1) v += __shfl_xor(v, o);
    __shared__ int s[4];
    if ((threadIdx.x & 63) == 0) s[threadIdx.x >> 6] = v;
    __syncthreads();
    if (threadIdx.x == 0) part[blockIdx.x] = s[0] + s[1] + s[2] + s[3];
}

// phase 2: exclusive scan of the <=256 partials (single block)
__global__ __launch_bounds__(256) void k_scanpart(int* __restrict__ part, int n) {
    int t = threadIdx.x;
    int v = (t < n) ? part[t] : 0;
    __shared__ int s[256];
    s[t] = v;
    __syncthreads();
#pragma unroll
    for (int d = 1; d < 256; d <<= 1) {
        int add = (t >= d) ? s[t - d] : 0;
        __syncthreads();
        s[t] += add;
        __syncthreads();
    }
    if (t < n) part[t] = s[t] - v;  // exclusive
}

// phase 3: block-local exclusive scan + partial offset; fuse dinv compute
__global__ __launch_bounds__(256) void k_scanfinal(const int* __restrict__ degi,
                                                   const int* __restrict__ part,
                                                   int* __restrict__ off,
                                                   float* __restrict__ dinv) {
    int b = blockIdx.x, t = threadIdx.x;
    int i = b * 256 + t;
    int v = (i < NN) ? degi[i] : 0;
    __shared__ int s[256];
    s[t] = v;
    __syncthreads();
#pragma unroll
    for (int d = 1; d < 256; d <<= 1) {
        int add = (t >= d) ? s[t - d] : 0;
        __syncthreads();
        s[t] += add;
        __syncthreads();
    }
    if (i < NN) {
        off[i] = part[b] + s[t] - v;
        dinv[i] = rsqrtf((float)v + 1.0f);  // +1 self-loop
    }
    if (i == 0) off[NN] = NE;  // total degree == edge count
}

// pure scatter, no atomics (rank captured in k_count_wt)
__global__ void k_fill(const int* __restrict__ src, const int* __restrict__ dst,
                       const int* __restrict__ off, const int* __restrict__ rank,
                       int* __restrict__ csrc) {
    int i = blockIdx.x * blockDim.x + threadIdx.x;
    if (i < NE) csrc[off[dst[i]] + rank[i]] = src[i];
}

// MFMA GEMM: out[row][:] = fp16( (A[row][:] @ W) * dinv[row] )
// BM=64 rows/block, 256 thr (4 waves, each wave: 16 rows x BN cols).
// A staged fp16 [64][128] XOR-swizzled; WT (=W^T fp16 [BN][128]) same swizzle.
// mfma_f32_16x16x32_f16: A row=lane&15, k=8*(lane>>4)+j; C/D col=lane&15,
// row=(lane>>4)*4+reg (m89-verified).
template <int BN, bool AF32>
__global__ __launch_bounds__(256) void k_gemm_mfma(
    const void* __restrict__ Ain, const h16* __restrict__ WT,
    const float* __restrict__ dinv, h16* __restrict__ out) {
    __shared__ h16x8 sXv[64 * 16];
    __shared__ h16x8 sWv[BN * 16];
    char* sX = (char*)sXv;
    char* sW = (char*)sWv;
    const int tid = threadIdx.x;
    const int row0 = blockIdx.x * 64;

    // ---- stage A: 1024 16B chunks (row, kb), swizzle byte ^= (row&7)<<4 ----
#pragma unroll
    for (int i = 0; i < 4; ++i) {
        int c = tid + i * 256;
        int row = c >> 4, kb = c & 15;
        int gr = row0 + row;
        h16x8 v = {};
        if (gr < NN) {
            if (AF32) {
                const float* src = (const float*)Ain + (size_t)gr * 128 + kb * 8;
                float4 u0 = *(const float4*)src;
                float4 u1 = *(const float4*)(src + 4);
                v[0] = (h16)u0.x; v[1] = (h16)u0.y; v[2] = (h16)u0.z; v[3] = (h16)u0.w;
                v[4] = (h16)u1.x; v[5] = (h16)u1.y; v[6] = (h16)u1.z; v[7] = (h16)u1.w;
            } else {
                v = *(const h16x8*)((const h16*)Ain + (size_t)gr * 128 + kb * 8);
            }
        }
        *(h16x8*)(sX + row * 256 + ((kb * 16) ^ ((row & 7) << 4))) = v;
    }
    // ---- stage WT: BN*16 chunks ----
#pragma unroll
    for (int i = 0; i < BN / 16; ++i) {
        int c = tid + i * 256;
        int n = c >> 4, kb = c & 15;
        h16x8 v = *(const h16x8*)&WT[(size_t)n * 128 + kb * 8];
        *(h16x8*)(sW + n * 256 + ((kb * 16) ^ ((n & 7) << 4))) = v;
    }
    __syncthreads();

    const int lane = tid & 63, wv = tid >> 6;
    const int g = lane >> 4, l15 = lane & 15;
    const int r = wv * 16 + l15;       // A row (local)
    f32x4 acc[BN / 16];
#pragma unroll
    for (int ct = 0; ct < BN / 16; ++ct) acc[ct] = (f32x4){0.f, 0.f, 0.f, 0.f};

#pragma unroll
    for (int t = 0; t < 4; ++t) {
        int kb2 = t * 64 + g * 16;     // byte offset of k-base within row
        h16x8 a = *(const h16x8*)(sX + r * 256 + (kb2 ^ ((r & 7) << 4)));
#pragma unroll
        for (int ct = 0; ct < BN / 16; ++ct) {
            int n = ct * 16 + l15;
            h16x8 b = *(const h16x8*)(sW + n * 256 + (kb2 ^ ((n & 7) << 4)));
            acc[ct] = __builtin_amdgcn_mfma_f32_16x16x32_f16(a, b, acc[ct], 0, 0, 0);
        }
    }

#pragma unroll
    for (int j = 0; j < 4; ++j) {
        int row = row0 + wv * 16 + g * 4 + j;
        if (row < NN) {
            float dv = dinv[row];
#pragma unroll
            for (int ct = 0; ct < BN / 16; ++ct)
                out[(size_t)row * BN + ct * 16 + l15] = (h16)(acc[ct][j] * dv);
        }
    }
}

// z1[n] = fp16(relu(dinv[n]*(sum h1[src] + h1[n]) + b))
// 32-lane group per node (h16x4/lane), 2 nodes/wave, no cross-lane reduce.
__global__ __launch_bounds__(256) void k_agg128(
    const h16x4* __restrict__ hs, const float* __restrict__ dinv,
    const int* __restrict__ off, const int* __restrict__ csrc,
    const float* __restrict__ bias, h16x4* __restrict__ z) {
    int node = blockIdx.x * 8 + (threadIdx.x >> 5);
    if (node >= NN) return;
    int col = threadIdx.x & 31;              // row = 32 h16x4
    int s = off[node], e = off[node + 1];
    float a0 = 0.f, a1 = 0.f, a2 = 0.f, a3 = 0.f;
    int j = s;
    for (; j + 8 <= e; j += 8) {
        int i0 = csrc[j],     i1 = csrc[j + 1], i2 = csrc[j + 2], i3 = csrc[j + 3];
        int i4 = csrc[j + 4], i5 = csrc[j + 5], i6 = csrc[j + 6], i7 = csrc[j + 7];
        h16x4 v0 = hs[(size_t)i0 * 32 + col];
        h16x4 v1 = hs[(size_t)i1 * 32 + col];
        h16x4 v2 = hs[(size_t)i2 * 32 + col];
        h16x4 v3 = hs[(size_t)i3 * 32 + col];
        h16x4 v4 = hs[(size_t)i4 * 32 + col];
        h16x4 v5 = hs[(size_t)i5 * 32 + col];
        h16x4 v6 = hs[(size_t)i6 * 32 + col];
        h16x4 v7 = hs[(size_t)i7 * 32 + col];
        a0 += ((float)v0.x + (float)v1.x + (float)v2.x + (float)v3.x) +
              ((float)v4.x + (float)v5.x + (float)v6.x + (float)v7.x);
        a1 += ((float)v0.y + (float)v1.y + (float)v2.y + (float)v3.y) +
              ((float)v4.y + (float)v5.y + (float)v6.y + (float)v7.y);
        a2 += ((float)v0.z + (float)v1.z + (float)v2.z + (float)v3.z) +
              ((float)v4.z + (float)v5.z + (float)v6.z + (float)v7.z);
        a3 += ((float)v0.w + (float)v1.w + (float)v2.w + (float)v3.w) +
              ((float)v4.w + (float)v5.w + (float)v6.w + (float)v7.w);
    }
    for (; j < e; ++j) {
        h16x4 v = hs[(size_t)csrc[j] * 32 + col];
        a0 += (float)v.x; a1 += (float)v.y; a2 += (float)v.z; a3 += (float)v.w;
    }
    h16x4 vs = hs[(size_t)node * 32 + col];  // self loop
    a0 += (float)vs.x; a1 += (float)vs.y; a2 += (float)vs.z; a3 += (float)vs.w;
    float dv = dinv[node];
    float4 bb = ((const float4*)bias)[col];
    float r0 = dv * a0 + bb.x, r1 = dv * a1 + bb.y;
    float r2 = dv * a2 + bb.z, r3 = dv * a3 + bb.w;
    h16x4 o;
    o.x = (h16)(r0 > 0.f ? r0 : 0.f); o.y = (h16)(r1 > 0.f ? r1 : 0.f);
    o.z = (h16)(r2 > 0.f ? r2 : 0.f); o.w = (h16)(r3 > 0.f ? r3 : 0.f);
    z[(size_t)node * 32 + col] = o;
}

// z2[n] = fp16(relu(dinv[n]*(sum h2[src] + h2[n]) + b))
// 16-lane group per node (h16x4/lane), 4 nodes/wave, no cross-lane reduce.
__global__ __launch_bounds__(256) void k_agg64(
    const h16x4* __restrict__ hs, const float* __restrict__ dinv,
    const int* __restrict__ off, const int* __restrict__ csrc,
    const float* __restrict__ bias, h16x4* __restrict__ z) {
    int node = blockIdx.x * 16 + (threadIdx.x >> 4);
    if (node >= NN) return;
    int col = threadIdx.x & 15;              // row = 16 h16x4
    int s = off[node], e = off[node + 1];
    float a0 = 0.f, a1 = 0.f, a2 = 0.f, a3 = 0.f;
    int j = s;
    for (; j + 8 <= e; j += 8) {
        int i0 = csrc[j],     i1 = csrc[j + 1], i2 = csrc[j + 2], i3 = csrc[j + 3];
        int i4 = csrc[j + 4], i5 = csrc[j + 5], i6 = csrc[j + 6], i7 = csrc[j + 7];
        h16x4 v0 = hs[(size_t)i0 * 16 + col];
        h16x4 v1 = hs[(size_t)i1 * 16 + col];
        h16x4 v2 = hs[(size_t)i2 * 16 + col];
        h16x4 v3 = hs[(size_t)i3 * 16 + col];
        h16x4 v4 = hs[(size_t)i4 * 16 + col];
        h16x4 v5 = hs[(size_t)i5 * 16 + col];
        h16x4 v6 = hs[(size_t)i6 * 16 + col];
        h16x4 v7 = hs[(size_t)i7 * 16 + col];
        a0 += ((float)v0.x + (float)v1.x + (float)v2.x + (float)v3.x) +
              ((float)v4.x + (float)v5.x + (float)v6.x + (float)v7.x);
        a1 += ((float)v0.y + (float)v1.y + (float)v2.y + (float)v3.y) +
              ((float)v4.y + (float)v5.y + (float)v6.y + (float)v7.y);
        a2 += ((float)v0.z + (float)v1.z + (float)v2.z + (float)v3.z) +
              ((float)v4.z + (float)v5.z + (float)v6.z + (float)v7.z);
        a3 += ((float)v0.w + (float)v1.w + (float)v2.w + (float)v3.w) +
              ((float)v4.w + (float)v5.w + (float)v6.w + (float)v7.w);
    }
    for (; j < e; ++j) {
        h16x4 v = hs[(size_t)csrc[j] * 16 + col];
        a0 += (float)v.x; a1 += (float)v.y; a2 += (float)v.z; a3 += (float)v.w;
    }
    h16x4 vs = hs[(size_t)node * 16 + col];  // self loop
    a0 += (float)vs.x; a1 += (float)vs.y; a2 += (float)vs.z; a3 += (float)vs.w;
    float dv = dinv[node];
    float4 bb = ((const float4*)bias)[col];
    float r0 = dv * a0 + bb.x, r1 = dv * a1 + bb.y;
    float r2 = dv * a2 + bb.z, r3 = dv * a3 + bb.w;
    h16x4 o;
    o.x = (h16)(r0 > 0.f ? r0 : 0.f); o.y = (h16)(r1 > 0.f ? r1 : 0.f);
    o.z = (h16)(r2 > 0.f ? r2 : 0.f); o.w = (h16)(r3 > 0.f ? r3 : 0.f);
    z[(size_t)node * 16 + col] = o;
}

// 8-lane groups, h16x8 (16B) loads, 4 pairs/group, 3-step shuffle reduce
__global__ __launch_bounds__(256) void k_dec(const h16* __restrict__ z2,
                                             const int* __restrict__ eli,
                                             float* __restrict__ out) {
    int g = blockIdx.x * 32 + (threadIdx.x >> 3);
    int p0 = g * 4;
    if (p0 >= ND) return;
    int sub = threadIdx.x & 7;
    float v[4];
#pragma unroll
    for (int q = 0; q < 4; ++q) {
        int ia = eli[p0 + q];
        int ib = eli[ND + p0 + q];
        h16x8 va = *(const h16x8*)&z2[(size_t)ia * DO + sub * 8];
        h16x8 vb = *(const h16x8*)&z2[(size_t)ib * DO + sub * 8];
        float acc = 0.f;
#pragma unroll
        for (int k = 0; k < 8; ++k) acc += (float)va[k] * (float)vb[k];
        v[q] = acc;
    }
#pragma unroll
    for (int o = 1; o < 8; o <<= 1) {
#pragma unroll
        for (int q = 0; q < 4; ++q) v[q] += __shfl_xor(v[q], o);
    }
    if (sub == 0) *(float4*)&out[p0] = make_float4(v[0], v[1], v[2], v[3]);
}

extern "C" void kernel_launch(void* const* d_in, const int* in_sizes, int n_in,
                              void* d_out, int out_size, void* d_ws, size_t ws_size,
                              hipStream_t stream) {
    const float* x  = (const float*)d_in[0];
    const float* Wi = (const float*)d_in[1];
    const float* bi = (const float*)d_in[2];
    const float* Wo = (const float*)d_in[3];
    const float* bo = (const float*)d_in[4];
    const int* ei   = (const int*)d_in[5];
    const int* eli  = (const int*)d_in[6];
    float* out = (float*)d_out;

    char* ws = (char*)d_ws;
    size_t o = 0;
    auto alloc = [&](size_t bytes) -> char* {
        char* p = ws + o;
        o = (o + bytes + 255) & ~(size_t)255;
        return p;
    };
    float* dinv = (float*)alloc(NN * 4);
    int* degi   = (int*)alloc(NN * 4);
    int* off    = (int*)alloc((NN + 1) * 4);
    int* part   = (int*)alloc(SCAN_GRID * 4);
    int* rank   = (int*)alloc((size_t)NE * 4);
    int* csrc   = (int*)alloc((size_t)NE * 4);
    h16* WiT    = (h16*)alloc(128 * 128 * 2);
    h16* WoT    = (h16*)alloc(64 * 128 * 2);
    h16* h1     = (h16*)alloc((size_t)NN * DH * 2);
    h16* z1     = (h16*)alloc((size_t)NN * DH * 2);
    h16* h2     = (h16*)alloc((size_t)NN * DO * 2);
    h16* z2     = (h16*)alloc((size_t)NN * DO * 2);

    const int* esrc = ei;
    const int* edst = ei + NE;

    hipMemsetAsync(degi, 0, NN * 4, stream);
    k_count_wt<<<CB + WTB, 256, 0, stream>>>(edst, degi, rank, Wi, Wo, WiT, WoT);
    k_blocksum<<<SCAN_GRID, 256, 0, stream>>>(degi, part);
    k_scanpart<<<1, 256, 0, stream>>>(part, SCAN_GRID);
    k_scanfinal<<<SCAN_GRID, 256, 0, stream>>>(degi, part, off, dinv);

    k_gemm_mfma<DH, true><<<(NN + 63) / 64, 256, 0, stream>>>(x, WiT, dinv, h1);
    k_fill<<<CB, 256, 0, stream>>>(esrc, edst, off, rank, csrc);

    k_agg128<<<(NN + 7) / 8, 256, 0, stream>>>((const h16x4*)h1, dinv, off, csrc, bi, (h16x4*)z1);
    k_gemm_mfma<DO, false><<<(NN + 63) / 64, 256, 0, stream>>>(z1, WoT, dinv, h2);
    k_agg64<<<(NN + 15) / 16, 256, 0, stream>>>((const h16x4*)h2, dinv, off, csrc, bo, (h16x4*)z2);

    k_dec<<<(ND + 127) / 128, 256, 0, stream>>>(z2, eli, out);
}